// Round 3
// baseline (540.222 us; speedup 1.0000x reference)
//
#include <hip/hip_runtime.h>
#include <cstdio>

typedef __bf16 bf16;
typedef __bf16 bf16x8 __attribute__((ext_vector_type(8)));
typedef __bf16 bf16x4 __attribute__((ext_vector_type(4)));
typedef float floatx4 __attribute__((ext_vector_type(4)));

#define T_TOK 4096
#define Dm    1024
#define Hm    512
#define Em    32
#define HsDim 1024   // shared inter dim
#define Pp    16384  // T*K pairs
#define CAP   2048   // per-expert capacity

// ---------------------------------------------------------------- gate ------
// logits[t][e] = x[t][:] . Wg[:][e] in fp32 (must match reference routing).
// 8 tokens/block; also writes the bf16 cast of x (x rows already in LDS).
__global__ __launch_bounds__(256) void gate_logits(
    const float* __restrict__ xf, const float* __restrict__ Wg,
    float* __restrict__ logits, bf16* __restrict__ xb)
{
    __shared__ float xs[8][Dm];        // 32 KB
    __shared__ float wsC[128 * Em];    // 16 KB, natural [d][e] layout
    int tid = threadIdx.x;
    int t0 = blockIdx.x * 8;

    const float4* src = (const float4*)(xf + (size_t)t0 * Dm);
    float4* dst = (float4*)&xs[0][0];
#pragma unroll
    for (int i = 0; i < 8; ++i) dst[tid + i * 256] = src[tid + i * 256];

    int tg = tid >> 5, e = tid & 31;
    float acc = 0.f;
    for (int d0 = 0; d0 < Dm; d0 += 128) {
        __syncthreads();               // covers xs on iter 0, wsC reuse after
        const float4* wg4 = (const float4*)(Wg + (size_t)d0 * Em);
        float4* ws4 = (float4*)wsC;
#pragma unroll
        for (int i = 0; i < 4; ++i) ws4[tid + i * 256] = wg4[tid + i * 256];
        __syncthreads();
#pragma unroll
        for (int d = 0; d < 128; d += 4) {
            float4 xv = *(const float4*)&xs[tg][d0 + d];
            acc = fmaf(xv.x, wsC[(d + 0) * Em + e], acc);
            acc = fmaf(xv.y, wsC[(d + 1) * Em + e], acc);
            acc = fmaf(xv.z, wsC[(d + 2) * Em + e], acc);
            acc = fmaf(xv.w, wsC[(d + 3) * Em + e], acc);
        }
    }
    logits[(size_t)(t0 + tg) * Em + e] = acc;

    // bf16 cast of the 8 staged rows (xs unchanged since load; already synced)
    bf16x4* xbrow = (bf16x4*)(xb + (size_t)t0 * Dm);
    const float4* xsf = (const float4*)&xs[0][0];
#pragma unroll
    for (int i = 0; i < 8; ++i) {
        int idx = tid + i * 256;
        float4 v = xsf[idx];
        bf16x4 o = {(bf16)v.x, (bf16)v.y, (bf16)v.z, (bf16)v.w};
        xbrow[idx] = o;
    }
}

// Per-token softmax + stable top-4 (ties -> lower index, same as lax.top_k).
__global__ __launch_bounds__(256) void gate_topk(
    const float* __restrict__ logits, int* __restrict__ topk_e,
    float* __restrict__ topk_w, int* __restrict__ cnt)
{
    __shared__ int hist[Em];
    int tid = threadIdx.x;
    if (tid < Em) hist[tid] = 0;
    __syncthreads();

    int t = blockIdx.x * 256 + tid;
    float l[Em];
    float M = -3.0e38f;
#pragma unroll
    for (int i = 0; i < 8; ++i) {
        float4 v = *(const float4*)(logits + (size_t)t * Em + i * 4);
        l[i * 4 + 0] = v.x; l[i * 4 + 1] = v.y;
        l[i * 4 + 2] = v.z; l[i * 4 + 3] = v.w;
        M = fmaxf(M, fmaxf(fmaxf(v.x, v.y), fmaxf(v.z, v.w)));
    }
    float sum = 0.f;
#pragma unroll
    for (int i = 0; i < Em; ++i) sum += __expf(l[i] - M);
    float inv = 1.0f / sum;
#pragma unroll
    for (int k = 0; k < 4; ++k) {
        float best = -3.0e38f; int bi = 0;
#pragma unroll
        for (int i = 0; i < Em; ++i)
            if (l[i] > best) { best = l[i]; bi = i; }
        topk_e[t * 4 + k] = bi;
        topk_w[t * 4 + k] = __expf(best - M) * inv;
        atomicAdd(&hist[bi], 1);
#pragma unroll
        for (int i = 0; i < Em; ++i)
            if (i == bi) l[i] = -3.0e38f;
    }
    __syncthreads();
    if (tid < Em) { int h = hist[tid]; if (h) atomicAdd(&cnt[tid], h); }
}

__global__ void offsets_kernel(const int* __restrict__ cnt, int* __restrict__ cntc,
                               int* __restrict__ offs)
{
    if (threadIdx.x == 0) {
        int run = 0;
        for (int e = 0; e < Em; ++e) {
            int c = cnt[e]; if (c > CAP) c = CAP;
            cntc[e] = c; offs[e] = run; run += c;
        }
        offs[Em] = run;
    }
}

// Records pair -> compact-row map (posC, -1 = capacity-dropped).
__global__ void scatter_kernel(const int* __restrict__ topk_e, const float* __restrict__ topk_w,
                               const int* __restrict__ cntc, const int* __restrict__ offs,
                               int* __restrict__ cnt2, int* __restrict__ tok_c,
                               float* __restrict__ wt_c, int* __restrict__ posC)
{
    int p = blockIdx.x * 256 + threadIdx.x;
    if (p >= Pp) return;
    int e = topk_e[p];
    int slot = atomicAdd(&cnt2[e], 1);
    int rc = -1;
    if (slot < cntc[e]) {
        rc = offs[e] + slot;
        tok_c[rc] = p >> 2;
        wt_c[rc] = topk_w[p];
    }
    posC[p] = rc;
}

// ---------------------------------------------------------------- casts -----
// 64x64 tile fp32->bf16 transpose. Block (64,4). Reads 256B/wave contiguous;
// LDS reads 2-way aliased (free per m136).
__device__ __forceinline__ void transpose_tile64(
    const float* __restrict__ src, bf16* __restrict__ dst, int R, int Cc)
{
    __shared__ float t[64][65];
    int r0 = blockIdx.y * 64, c0 = blockIdx.x * 64;
    int tx = threadIdx.x, ty = threadIdx.y;
#pragma unroll
    for (int i = 0; i < 16; ++i) {
        int row = ty + i * 4;
        t[row][tx] = src[(long)(r0 + row) * Cc + (c0 + tx)];
    }
    __syncthreads();
#pragma unroll
    for (int i = 0; i < 16; ++i) {
        int row = ty + i * 4;
        dst[(long)(c0 + row) * R + (r0 + tx)] = (bf16)t[tx][row];
    }
}

// W1 (z<32) and W3 (z>=32): (Dm x Hm) -> rows [0,512) / [512,1024) of the
// per-expert 1024 x Dm block of W13T.
__global__ __launch_bounds__(256) void transpose_w13(
    const float* __restrict__ W1, const float* __restrict__ W3,
    bf16* __restrict__ W13T)
{
    int z = blockIdx.z;
    int e = z & 31;
    const float* src = (z < 32 ? W1 : W3) + (long)e * Dm * Hm;
    bf16* dst = W13T + (long)e * 2 * Hm * Dm + (z < 32 ? 0 : (long)Hm * Dm);
    transpose_tile64(src, dst, Dm, Hm);
}

// W2[e]: (Hm x Dm) -> (Dm x Hm)
__global__ __launch_bounds__(256) void transpose_w2(
    const float* __restrict__ W2, bf16* __restrict__ W2T)
{
    int e = blockIdx.z;
    transpose_tile64(W2 + (long)e * Hm * Dm, W2T + (long)e * Hm * Dm, Hm, Dm);
}

// Ws1 / Ws3 / Ws2, each (1024 x 1024), selected by z.
__global__ __launch_bounds__(256) void transpose_ws(
    const float* __restrict__ Ws1, const float* __restrict__ Ws3,
    const float* __restrict__ Ws2, bf16* __restrict__ Ws13T,
    bf16* __restrict__ Ws2T)
{
    int z = blockIdx.z;
    const float* src = z == 0 ? Ws1 : (z == 1 ? Ws3 : Ws2);
    bf16* dst = z == 0 ? Ws13T : (z == 1 ? Ws13T + (long)HsDim * Dm : Ws2T);
    transpose_tile64(src, dst, Dm, Dm);
}

// ---------------------------------------------------------------- GEMM ------
// 128x128 tile, BK=32, 4 waves (64x64 each), mfma_f32_16x16x32_bf16.
// Depth-2 pipeline, ONE barrier per K-step (same count as the verified R1
// structure): 3 LDS buffers, counted vmcnt (T4), stage(kt+2) issued right
// after the entry barrier into the buffer whose reads finished last iter.
// Safety: a wave reaches the entry barrier only after its ds_read values
// were consumed by MFMA (compiler-enforced lgkmcnt), so post-barrier writes
// into buf (kt+2)%3 == (kt-1)%3 cannot race any reader. All raw s_barriers
// are pinned with sched_barrier(0) on both sides; waitcnt asm carries a
// "memory" clobber, so no memory op crosses a sync point.
//
// Swizzle (BK=32, 64B rows, 4x 16B chunks/row): LDS slot for chunk q of row
// r is q ^ ((r>>1)&3); inverse permutation applied to the per-lane GLOBAL
// address (LDS dest stays linear, as global_load_lds requires).
__device__ __forceinline__ void gload_lds16(const bf16* g, bf16* l)
{
    __builtin_amdgcn_global_load_lds((const __attribute__((address_space(1))) void*)g,
                                     (__attribute__((address_space(3))) void*)l, 16, 0, 0);
}

__device__ __forceinline__ void pinned_barrier()
{
    __builtin_amdgcn_sched_barrier(0);
    __builtin_amdgcn_s_barrier();
    __builtin_amdgcn_sched_barrier(0);
}

// Merged GEMM1 (+fused SwiGLU), flat 1-D grid (2304 blocks) with XCD-chunked
// swizzle: lid = (bid&7)*288 + bid>>3 makes lid-consecutive blocks co-XCD
// (round-robin dispatch assumption; perf-only). lid < 2048 -> routed
// (e=lid>>6, nt=(lid>>4)&3, mt=lid&15): the 16 m-tiles sharing one expert's
// B-panel are lid-consecutive -> same XCD L2. lid >= 2048 -> shared
// (nt=s>>5, mt=s&31).
__global__ void __launch_bounds__(256, 2) gemm1_merged(
    const bf16* __restrict__ xb, const bf16* __restrict__ W13T,
    const bf16* __restrict__ Ws13T,
    const int* __restrict__ cntc, const int* __restrict__ offs,
    const int* __restrict__ tok,
    bf16* __restrict__ Hh, bf16* __restrict__ HhS)
{
    __shared__ __align__(16) bf16 sm[3][3][128 * 32];   // 72 KB (3buf A,B1,B3)

    int bid = blockIdx.x;
    int lid = (bid & 7) * 288 + (bid >> 3);

    int mt, mcount, rowbase, ntile;
    const bf16* BT;
    bf16* outH;
    int ldo;
    long off3;
    bool gather;
    if (lid < 2048) {
        int e = lid >> 6;
        ntile = (lid >> 4) & 3;
        mt = lid & 15;
        mcount = cntc[e];
        if (mt * 128 >= mcount) return;
        rowbase = offs[e];
        BT = W13T + (long)e * 2 * Hm * Dm;
        outH = Hh; ldo = Hm; off3 = (long)Hm * Dm;
        gather = true;
    } else {
        int s = lid - 2048;            // 256 shared blocks: 32 mt x 8 nt
        ntile = s >> 5;
        mt = s & 31;
        mcount = T_TOK; rowbase = 0;
        BT = Ws13T;
        outH = HhS; ldo = HsDim; off3 = (long)HsDim * Dm;
        gather = false;
    }

    int tid = threadIdx.x;
    int wave = tid >> 6, lane = tid & 63;
    int wm = wave >> 1, wn = wave & 1;
    int q = lane >> 4, lm = lane & 15;

    floatx4 acc1[4][4] = {};
    floatx4 acc3[4][4] = {};

    // Staging addresses (kt-invariant): 2 instrs per matrix per wave.
    const bf16* aG[2];
    const bf16* bG[2];
    int ldsOff[2];
#pragma unroll
    for (int it = 0; it < 2; ++it) {
        int c = wave * 128 + it * 64 + lane;
        int row = c >> 2;
        int g = (c & 3) ^ ((row >> 1) & 3);
        int rl = mt * 128 + row;
        int rr = rl < mcount ? rl : mcount - 1;
        long aoff;
        if (gather) aoff = (long)tok[rowbase + rr] * Dm;
        else        aoff = (long)rr * Dm;
        aG[it] = xb + aoff + g * 8;
        bG[it] = BT + (long)(ntile * 128 + row) * Dm + g * 8;
        ldsOff[it] = (wave * 128 + it * 64) * 8;   // linear dest, 128B/instr
    }

    // LDS fragment element-offsets (kt-invariant, swizzled)
    int aoffL[4], boffL[4];
#pragma unroll
    for (int i = 0; i < 4; ++i) {
        int ra = wm * 64 + i * 16 + lm;
        int rb = wn * 64 + i * 16 + lm;
        aoffL[i] = ra * 32 + ((q ^ ((ra >> 1) & 3)) * 8);
        boffL[i] = rb * 32 + ((q ^ ((rb >> 1) & 3)) * 8);
    }

    auto stage = [&](int buf, int kt) {
#pragma unroll
        for (int it = 0; it < 2; ++it) {
            gload_lds16(aG[it] + (long)kt * 32,        &sm[buf][0][ldsOff[it]]);
            gload_lds16(bG[it] + (long)kt * 32,        &sm[buf][1][ldsOff[it]]);
            gload_lds16(bG[it] + off3 + (long)kt * 32, &sm[buf][2][ldsOff[it]]);
        }
    };

#define G1_COMPUTE()                                                       \
    {                                                                      \
        const bf16* A_  = &sm[cur][0][0];                                  \
        const bf16* B1_ = &sm[cur][1][0];                                  \
        const bf16* B3_ = &sm[cur][2][0];                                  \
        bf16x8 af[4], b1v[4], b3v[4];                                      \
        _Pragma("unroll")                                                  \
        for (int i = 0; i < 4; ++i) {                                      \
            af[i]  = *(const bf16x8*)(A_  + aoffL[i]);                     \
            b1v[i] = *(const bf16x8*)(B1_ + boffL[i]);                     \
            b3v[i] = *(const bf16x8*)(B3_ + boffL[i]);                     \
        }                                                                  \
        __builtin_amdgcn_sched_barrier(0);                                 \
        __builtin_amdgcn_s_setprio(1);                                     \
        _Pragma("unroll")                                                  \
        for (int i = 0; i < 4; ++i)                                        \
            _Pragma("unroll")                                              \
            for (int j2 = 0; j2 < 4; ++j2) {                               \
                acc1[i][j2] = __builtin_amdgcn_mfma_f32_16x16x32_bf16(     \
                    af[i], b1v[j2], acc1[i][j2], 0, 0, 0);                 \
                acc3[i][j2] = __builtin_amdgcn_mfma_f32_16x16x32_bf16(     \
                    af[i], b3v[j2], acc3[i][j2], 0, 0, 0);                 \
            }                                                              \
        __builtin_amdgcn_s_setprio(0);                                     \
        cur = (cur == 2) ? 0 : cur + 1;                                    \
    }

    const int NT = Dm / 32;            // 32
    int cur = 0;
    stage(0, 0);
    stage(1, 1);
    for (int kt = 0; kt < NT - 2; ++kt) {
        asm volatile("s_waitcnt vmcnt(6)" ::: "memory");   // stage kt landed
        pinned_barrier();
        int nb = cur + 2; if (nb >= 3) nb -= 3;            // held stage kt-1
        stage(nb, kt + 2);
        G1_COMPUTE();
    }
    asm volatile("s_waitcnt vmcnt(6)" ::: "memory");       // kt = NT-2
    pinned_barrier();
    G1_COMPUTE();
    asm volatile("s_waitcnt vmcnt(0)" ::: "memory");       // kt = NT-1
    pinned_barrier();
    G1_COMPUTE();
#undef G1_COMPUTE

    int colbase = ntile * 128 + wn * 64;
#pragma unroll
    for (int i = 0; i < 4; ++i) {
        int rloc = wm * 64 + i * 16 + q * 4;
#pragma unroll
        for (int r = 0; r < 4; ++r) {
            int rl = mt * 128 + rloc + r;
            if (rl >= mcount) continue;
#pragma unroll
            for (int j2 = 0; j2 < 4; ++j2) {
                int col = colbase + j2 * 16 + lm;
                float a = acc1[i][j2][r], b = acc3[i][j2][r];
                float sg = 1.0f / (1.0f + __expf(-a));
                outH[(long)(rowbase + rl) * ldo + col] = (bf16)(a * sg * b);
            }
        }
    }
}

// Merged GEMM2: same depth-2 pipeline (4 loads/stage -> vmcnt 4/0 peel).
// Flat 4352-block grid, XCD-chunked. lid < 4096 -> routed (e=lid>>7,
// nt=(lid>>4)&7, mt=lid&15; A=Hh K=512, bf16 compact store to Yc);
// else shared (nt=s>>5, mt=s&31; A=HhS K=1024, fp32 store to out).
__global__ void __launch_bounds__(256, 2) gemm2_merged(
    const bf16* __restrict__ Hh, const bf16* __restrict__ HhS,
    const bf16* __restrict__ W2T, const bf16* __restrict__ Ws2T,
    const int* __restrict__ cntc, const int* __restrict__ offs,
    bf16* __restrict__ Yc, float* __restrict__ out)
{
    __shared__ __align__(16) bf16 sm[3][2][128 * 32];   // 48 KB (3buf A,B)

    int bid = blockIdx.x;
    int lid = (bid & 7) * 544 + (bid >> 3);

    int mt, mcount, rowbase, K, lda, nt;
    const bf16* A;
    const bf16* BT;
    bool toBf;
    if (lid < 4096) {
        int e = lid >> 7;
        nt = (lid >> 4) & 7;
        mt = lid & 15;
        mcount = cntc[e];
        if (mt * 128 >= mcount) return;
        rowbase = offs[e];
        A = Hh; lda = Hm; K = Hm;
        BT = W2T + (long)e * Hm * Dm;
        toBf = true;
    } else {
        int s = lid - 4096;            // 256 shared blocks: 8 nt x 32 mt
        nt = s >> 5;
        mt = s & 31;
        mcount = T_TOK; rowbase = 0;
        A = HhS; lda = HsDim; K = HsDim;
        BT = Ws2T;
        toBf = false;
    }

    int tid = threadIdx.x;
    int wave = tid >> 6, lane = tid & 63;
    int wm = wave >> 1, wn = wave & 1;
    int q = lane >> 4, lm = lane & 15;

    floatx4 acc[4][4] = {};

    const bf16* aG[2];
    const bf16* bG[2];
    int ldsOff[2];
#pragma unroll
    for (int it = 0; it < 2; ++it) {
        int c = wave * 128 + it * 64 + lane;
        int row = c >> 2;
        int g = (c & 3) ^ ((row >> 1) & 3);
        int rl = mt * 128 + row;
        int rr = rl < mcount ? rl : mcount - 1;
        aG[it] = A + (long)(rowbase + rr) * lda + g * 8;
        bG[it] = BT + (long)(nt * 128 + row) * K + g * 8;
        ldsOff[it] = (wave * 128 + it * 64) * 8;
    }

    int aoffL[4], boffL[4];
#pragma unroll
    for (int i = 0; i < 4; ++i) {
        int ra = wm * 64 + i * 16 + lm;
        int rb = wn * 64 + i * 16 + lm;
        aoffL[i] = ra * 32 + ((q ^ ((ra >> 1) & 3)) * 8);
        boffL[i] = rb * 32 + ((q ^ ((rb >> 1) & 3)) * 8);
    }

    auto stage = [&](int buf, int kt) {
#pragma unroll
        for (int it = 0; it < 2; ++it) {
            gload_lds16(aG[it] + (long)kt * 32, &sm[buf][0][ldsOff[it]]);
            gload_lds16(bG[it] + (long)kt * 32, &sm[buf][1][ldsOff[it]]);
        }
    };

#define G2_COMPUTE()                                                       \
    {                                                                      \
        const bf16* A_ = &sm[cur][0][0];                                   \
        const bf16* B_ = &sm[cur][1][0];                                   \
        bf16x8 af[4], bfv[4];                                              \
        _Pragma("unroll")                                                  \
        for (int i = 0; i < 4; ++i) {                                      \
            af[i]  = *(const bf16x8*)(A_ + aoffL[i]);                      \
            bfv[i] = *(const bf16x8*)(B_ + boffL[i]);                      \
        }                                                                  \
        __builtin_amdgcn_sched_barrier(0);                                 \
        __builtin_amdgcn_s_setprio(1);                                     \
        _Pragma("unroll")                                                  \
        for (int i = 0; i < 4; ++i)                                        \
            _Pragma("unroll")                                              \
            for (int j2 = 0; j2 < 4; ++j2)                                 \
                acc[i][j2] = __builtin_amdgcn_mfma_f32_16x16x32_bf16(      \
                    af[i], bfv[j2], acc[i][j2], 0, 0, 0);                  \
        __builtin_amdgcn_s_setprio(0);                                     \
        cur = (cur == 2) ? 0 : cur + 1;                                    \
    }

    const int NT = K / 32;             // 16 or 32 (block-uniform)
    int cur = 0;
    stage(0, 0);
    stage(1, 1);
    for (int kt = 0; kt < NT - 2; ++kt) {
        asm volatile("s_waitcnt vmcnt(4)" ::: "memory");
        pinned_barrier();
        int nb = cur + 2; if (nb >= 3) nb -= 3;
        stage(nb, kt + 2);
        G2_COMPUTE();
    }
    asm volatile("s_waitcnt vmcnt(4)" ::: "memory");
    pinned_barrier();
    G2_COMPUTE();
    asm volatile("s_waitcnt vmcnt(0)" ::: "memory");
    pinned_barrier();
    G2_COMPUTE();
#undef G2_COMPUTE

    int colbase = nt * 128 + wn * 64;
#pragma unroll
    for (int i = 0; i < 4; ++i) {
        int rloc = wm * 64 + i * 16 + q * 4;
#pragma unroll
        for (int r = 0; r < 4; ++r) {
            int rl = mt * 128 + rloc + r;
            if (rl >= mcount) continue;
#pragma unroll
            for (int j2 = 0; j2 < 4; ++j2) {
                int col = colbase + j2 * 16 + lm;
                float v = acc[i][j2][r];
                if (toBf) Yc[(long)(rowbase + rl) * Dm + col] = (bf16)v;
                else      out[(long)rl * Dm + col] = v;
            }
        }
    }
}

// ------------------------------------------------------------- combine ------
// out[t][:] += sum_k w[t,k] * Yc[posC[t*4+k]][:]  (posC<0 => dropped pair).
__global__ __launch_bounds__(256) void combine_kernel(
    const bf16* __restrict__ Yc, const float* __restrict__ topkW,
    const int* __restrict__ posC, float* __restrict__ out)
{
    __shared__ int   sp[4];
    __shared__ float sw[4];
    int t = blockIdx.x, tid = threadIdx.x;
    if (tid < 4) {
        sp[tid] = posC[t * 4 + tid];
        sw[tid] = topkW[t * 4 + tid];
    }
    __syncthreads();
    int d = tid * 4;
    float4 o = *(float4*)(out + (size_t)t * Dm + d);
#pragma unroll
    for (int k = 0; k < 4; ++k) {
        int rc = sp[k];
        if (rc >= 0) {
            bf16x4 v = *(const bf16x4*)(Yc + (size_t)rc * Dm + d);
            float w = sw[k];
            o.x += w * (float)v[0];
            o.y += w * (float)v[1];
            o.z += w * (float)v[2];
            o.w += w * (float)v[3];
        }
    }
    *(float4*)(out + (size_t)t * Dm + d) = o;
}

// ---------------------------------------------------------------- launch ----
extern "C" void kernel_launch(void* const* d_in, const int* in_sizes, int n_in,
                              void* d_out, int out_size, void* d_ws, size_t ws_size,
                              hipStream_t stream)
{
    const float* x   = (const float*)d_in[0];
    const float* Wg  = (const float*)d_in[1];
    const float* W1  = (const float*)d_in[2];
    const float* W2  = (const float*)d_in[3];
    const float* W3  = (const float*)d_in[4];
    const float* Ws1 = (const float*)d_in[5];
    const float* Ws2 = (const float*)d_in[6];
    const float* Ws3 = (const float*)d_in[7];
    float* out = (float*)d_out;

    char* p = (char*)d_ws;
    auto alloc = [&](size_t bytes) {
        char* r = p; p += (bytes + 255) & ~(size_t)255; return r;
    };
    bf16*  xb    = (bf16*)alloc((size_t)T_TOK * Dm * 2);
    bf16*  W13T  = (bf16*)alloc((size_t)Em * 2 * Hm * Dm * 2);
    bf16*  W2T   = (bf16*)alloc((size_t)Em * Dm * Hm * 2);
    bf16*  Ws13T = (bf16*)alloc((size_t)2 * HsDim * Dm * 2);
    bf16*  Ws2T  = (bf16*)alloc((size_t)Dm * HsDim * 2);
    bf16*  Yc    = (bf16*)alloc((size_t)Pp * Dm * 2);      // expert GEMM2 compact out
    bf16*  Hh    = (bf16*)alloc((size_t)Pp * Hm * 2);      // expert hidden (compact)
    bf16*  HhS   = (bf16*)alloc((size_t)T_TOK * HsDim * 2);// shared hidden
    float* logits= (float*)alloc((size_t)T_TOK * Em * 4);
    int*   topkE = (int*)alloc(Pp * 4);
    float* topkW = (float*)alloc(Pp * 4);
    int*   tokC  = (int*)alloc(Pp * 4);
    float* wtC   = (float*)alloc(Pp * 4);
    int*   posC  = (int*)alloc(Pp * 4);
    int*   cnt   = (int*)alloc(128);
    int*   cnt2  = (int*)alloc(128);
    int*   cntc  = (int*)alloc(128);
    int*   offs  = (int*)alloc(256);

    size_t need = (size_t)(p - (char*)d_ws);
    if (ws_size < need) {
        fprintf(stderr, "kernel_launch: ws too small (%zu < %zu)\n", ws_size, need);
        return;
    }

    hipMemsetAsync(cnt, 0, 1024, stream);  // cnt, cnt2, cntc, offs

    // Routing (fp32, matches reference top-k exactly) + x bf16 cast
    gate_logits<<<T_TOK / 8, 256, 0, stream>>>(x, Wg, logits, xb);
    gate_topk<<<T_TOK / 256, 256, 0, stream>>>(logits, topkE, topkW, cnt);
    offsets_kernel<<<1, 64, 0, stream>>>(cnt, cntc, offs);
    scatter_kernel<<<Pp / 256, 256, 0, stream>>>(topkE, topkW, cntc, offs, cnt2,
                                                 tokC, wtC, posC);

    // weight transposes+casts (3 dispatches)
    transpose_w13<<<dim3(Hm / 64, Dm / 64, 2 * Em), dim3(64, 4), 0, stream>>>(W1, W3, W13T);
    transpose_w2 <<<dim3(Dm / 64, Hm / 64, Em),     dim3(64, 4), 0, stream>>>(W2, W2T);
    transpose_ws <<<dim3(Dm / 64, Dm / 64, 3),      dim3(64, 4), 0, stream>>>(
        Ws1, Ws3, Ws2, Ws13T, Ws2T);

    // GEMM1 (both paths, fused SwiGLU) -> GEMM2 (both paths) -> combine
    gemm1_merged<<<dim3(2304), 256, 0, stream>>>(
        xb, W13T, Ws13T, cntc, offs, tokC, Hh, HhS);
    gemm2_merged<<<dim3(4352), 256, 0, stream>>>(
        Hh, HhS, W2T, Ws2T, cntc, offs, Yc, out);
    combine_kernel<<<T_TOK, 256, 0, stream>>>(Yc, topkW, posC, out);
}

// Round 4
// 535.622 us; speedup vs baseline: 1.0086x; 1.0086x over previous
//
#include <hip/hip_runtime.h>
#include <cstdio>

typedef __bf16 bf16;
typedef __bf16 bf16x8 __attribute__((ext_vector_type(8)));
typedef __bf16 bf16x4 __attribute__((ext_vector_type(4)));
typedef float floatx4 __attribute__((ext_vector_type(4)));

#define T_TOK 4096
#define Dm    1024
#define Hm    512
#define Em    32
#define HsDim 1024   // shared inter dim
#define Pp    16384  // T*K pairs
#define CAP   2048   // per-expert capacity

// ---------------------------------------------------------------- gate ------
// logits[t][e] = x[t][:] . Wg[:][e] in fp32 (must match reference routing).
// 8 tokens/block; also writes the bf16 cast of x (x rows already in LDS).
__global__ __launch_bounds__(256) void gate_logits(
    const float* __restrict__ xf, const float* __restrict__ Wg,
    float* __restrict__ logits, bf16* __restrict__ xb)
{
    __shared__ float xs[8][Dm];        // 32 KB
    __shared__ float wsC[128 * Em];    // 16 KB, natural [d][e] layout
    int tid = threadIdx.x;
    int t0 = blockIdx.x * 8;

    const float4* src = (const float4*)(xf + (size_t)t0 * Dm);
    float4* dst = (float4*)&xs[0][0];
#pragma unroll
    for (int i = 0; i < 8; ++i) dst[tid + i * 256] = src[tid + i * 256];

    int tg = tid >> 5, e = tid & 31;
    float acc = 0.f;
    for (int d0 = 0; d0 < Dm; d0 += 128) {
        __syncthreads();               // covers xs on iter 0, wsC reuse after
        const float4* wg4 = (const float4*)(Wg + (size_t)d0 * Em);
        float4* ws4 = (float4*)wsC;
#pragma unroll
        for (int i = 0; i < 4; ++i) ws4[tid + i * 256] = wg4[tid + i * 256];
        __syncthreads();
#pragma unroll
        for (int d = 0; d < 128; d += 4) {
            float4 xv = *(const float4*)&xs[tg][d0 + d];
            acc = fmaf(xv.x, wsC[(d + 0) * Em + e], acc);
            acc = fmaf(xv.y, wsC[(d + 1) * Em + e], acc);
            acc = fmaf(xv.z, wsC[(d + 2) * Em + e], acc);
            acc = fmaf(xv.w, wsC[(d + 3) * Em + e], acc);
        }
    }
    logits[(size_t)(t0 + tg) * Em + e] = acc;

    // bf16 cast of the 8 staged rows (xs unchanged since load; already synced)
    bf16x4* xbrow = (bf16x4*)(xb + (size_t)t0 * Dm);
    const float4* xsf = (const float4*)&xs[0][0];
#pragma unroll
    for (int i = 0; i < 8; ++i) {
        int idx = tid + i * 256;
        float4 v = xsf[idx];
        bf16x4 o = {(bf16)v.x, (bf16)v.y, (bf16)v.z, (bf16)v.w};
        xbrow[idx] = o;
    }
}

// Per-token softmax + stable top-4 (ties -> lower index, same as lax.top_k).
__global__ __launch_bounds__(256) void gate_topk(
    const float* __restrict__ logits, int* __restrict__ topk_e,
    float* __restrict__ topk_w, int* __restrict__ cnt)
{
    __shared__ int hist[Em];
    int tid = threadIdx.x;
    if (tid < Em) hist[tid] = 0;
    __syncthreads();

    int t = blockIdx.x * 256 + tid;
    float l[Em];
    float M = -3.0e38f;
#pragma unroll
    for (int i = 0; i < 8; ++i) {
        float4 v = *(const float4*)(logits + (size_t)t * Em + i * 4);
        l[i * 4 + 0] = v.x; l[i * 4 + 1] = v.y;
        l[i * 4 + 2] = v.z; l[i * 4 + 3] = v.w;
        M = fmaxf(M, fmaxf(fmaxf(v.x, v.y), fmaxf(v.z, v.w)));
    }
    float sum = 0.f;
#pragma unroll
    for (int i = 0; i < Em; ++i) sum += __expf(l[i] - M);
    float inv = 1.0f / sum;
#pragma unroll
    for (int k = 0; k < 4; ++k) {
        float best = -3.0e38f; int bi = 0;
#pragma unroll
        for (int i = 0; i < Em; ++i)
            if (l[i] > best) { best = l[i]; bi = i; }
        topk_e[t * 4 + k] = bi;
        topk_w[t * 4 + k] = __expf(best - M) * inv;
        atomicAdd(&hist[bi], 1);
#pragma unroll
        for (int i = 0; i < Em; ++i)
            if (i == bi) l[i] = -3.0e38f;
    }
    __syncthreads();
    if (tid < Em) { int h = hist[tid]; if (h) atomicAdd(&cnt[tid], h); }
}

__global__ void offsets_kernel(const int* __restrict__ cnt, int* __restrict__ cntc,
                               int* __restrict__ offs)
{
    if (threadIdx.x == 0) {
        int run = 0;
        for (int e = 0; e < Em; ++e) {
            int c = cnt[e]; if (c > CAP) c = CAP;
            cntc[e] = c; offs[e] = run; run += c;
        }
        offs[Em] = run;
    }
}

// Records pair -> compact-row map (posC, -1 = capacity-dropped).
__global__ void scatter_kernel(const int* __restrict__ topk_e, const float* __restrict__ topk_w,
                               const int* __restrict__ cntc, const int* __restrict__ offs,
                               int* __restrict__ cnt2, int* __restrict__ tok_c,
                               float* __restrict__ wt_c, int* __restrict__ posC)
{
    int p = blockIdx.x * 256 + threadIdx.x;
    if (p >= Pp) return;
    int e = topk_e[p];
    int slot = atomicAdd(&cnt2[e], 1);
    int rc = -1;
    if (slot < cntc[e]) {
        rc = offs[e] + slot;
        tok_c[rc] = p >> 2;
        wt_c[rc] = topk_w[p];
    }
    posC[p] = rc;
}

// ---------------------------------------------------------------- casts -----
// 64x64 tile fp32->bf16 transpose. Block (64,4). Reads 256B/wave contiguous;
// LDS reads 2-way aliased (free per m136).
__device__ __forceinline__ void transpose_tile64(
    const float* __restrict__ src, bf16* __restrict__ dst, int R, int Cc)
{
    __shared__ float t[64][65];
    int r0 = blockIdx.y * 64, c0 = blockIdx.x * 64;
    int tx = threadIdx.x, ty = threadIdx.y;
#pragma unroll
    for (int i = 0; i < 16; ++i) {
        int row = ty + i * 4;
        t[row][tx] = src[(long)(r0 + row) * Cc + (c0 + tx)];
    }
    __syncthreads();
#pragma unroll
    for (int i = 0; i < 16; ++i) {
        int row = ty + i * 4;
        dst[(long)(c0 + row) * R + (r0 + tx)] = (bf16)t[tx][row];
    }
}

// W1 (z<32) and W3 (z>=32): (Dm x Hm) -> rows [0,512) / [512,1024) of the
// per-expert 1024 x Dm block of W13T.
__global__ __launch_bounds__(256) void transpose_w13(
    const float* __restrict__ W1, const float* __restrict__ W3,
    bf16* __restrict__ W13T)
{
    int z = blockIdx.z;
    int e = z & 31;
    const float* src = (z < 32 ? W1 : W3) + (long)e * Dm * Hm;
    bf16* dst = W13T + (long)e * 2 * Hm * Dm + (z < 32 ? 0 : (long)Hm * Dm);
    transpose_tile64(src, dst, Dm, Hm);
}

// W2[e]: (Hm x Dm) -> (Dm x Hm)
__global__ __launch_bounds__(256) void transpose_w2(
    const float* __restrict__ W2, bf16* __restrict__ W2T)
{
    int e = blockIdx.z;
    transpose_tile64(W2 + (long)e * Hm * Dm, W2T + (long)e * Hm * Dm, Hm, Dm);
}

// Ws1 / Ws3 / Ws2, each (1024 x 1024), selected by z.
__global__ __launch_bounds__(256) void transpose_ws(
    const float* __restrict__ Ws1, const float* __restrict__ Ws3,
    const float* __restrict__ Ws2, bf16* __restrict__ Ws13T,
    bf16* __restrict__ Ws2T)
{
    int z = blockIdx.z;
    const float* src = z == 0 ? Ws1 : (z == 1 ? Ws3 : Ws2);
    bf16* dst = z == 0 ? Ws13T : (z == 1 ? Ws13T + (long)HsDim * Dm : Ws2T);
    transpose_tile64(src, dst, Dm, Dm);
}

// ---------------------------------------------------------------- GEMM ------
// 128x128 tile, BK=32, 4 waves (64x64 each), mfma_f32_16x16x32_bf16.
// R1-verified 2-phase double-buffered pipeline (105 us gemm1): prefetch for
// tile kt+1 issued immediately after __syncthreads, so the vmcnt(0) drain in
// the NEXT barrier lands after a full ds_read+MFMA phase. Compiler-scheduled
// (no sched_barrier pinning — m141/R3 regression), 48 KB LDS (3 blocks/CU).
//
// Swizzle (BK=32, 64B rows, 4x 16B chunks/row): LDS slot for chunk q of row
// r is q ^ ((r>>1)&3); inverse permutation applied to the per-lane GLOBAL
// address (LDS dest stays linear, as global_load_lds requires).
__device__ __forceinline__ void gload_lds16(const bf16* g, bf16* l)
{
    __builtin_amdgcn_global_load_lds((const __attribute__((address_space(1))) void*)g,
                                     (__attribute__((address_space(3))) void*)l, 16, 0, 0);
}

// Merged GEMM1 (+fused SwiGLU), flat 1-D grid (2304 blocks) with XCD-chunked
// swizzle: lid = (bid&7)*288 + bid>>3 makes lid-consecutive blocks co-XCD
// (R3 evidence: FETCH_SIZE 137->91 MB). lid < 2048 -> routed (e=lid>>6,
// ntile=(lid>>4)&3, mt=lid&15): the 16 m-tiles sharing one expert's B-panel
// are lid-consecutive -> same XCD L2. lid >= 2048 -> shared (s=lid-2048,
// ntile=s>>5, mt=s&31).
__global__ void __launch_bounds__(256, 2) gemm1_merged(
    const bf16* __restrict__ xb, const bf16* __restrict__ W13T,
    const bf16* __restrict__ Ws13T,
    const int* __restrict__ cntc, const int* __restrict__ offs,
    const int* __restrict__ tok,
    bf16* __restrict__ Hh, bf16* __restrict__ HhS)
{
    __shared__ __align__(16) bf16 sm[2][3][128 * 32];   // 48 KB (dbuf A,B1,B3)

    int bid = blockIdx.x;
    int lid = (bid & 7) * 288 + (bid >> 3);

    int mt, mcount, rowbase, ntile;
    const bf16* BT;
    bf16* outH;
    int ldo;
    long off3;
    bool gather;
    if (lid < 2048) {
        int e = lid >> 6;
        ntile = (lid >> 4) & 3;
        mt = lid & 15;
        mcount = cntc[e];
        if (mt * 128 >= mcount) return;
        rowbase = offs[e];
        BT = W13T + (long)e * 2 * Hm * Dm;
        outH = Hh; ldo = Hm; off3 = (long)Hm * Dm;
        gather = true;
    } else {
        int s = lid - 2048;            // 256 shared blocks: 8 nt x 32 mt
        ntile = s >> 5;
        mt = s & 31;
        mcount = T_TOK; rowbase = 0;
        BT = Ws13T;
        outH = HhS; ldo = HsDim; off3 = (long)HsDim * Dm;
        gather = false;
    }

    int tid = threadIdx.x;
    int wave = tid >> 6, lane = tid & 63;
    int wm = wave >> 1, wn = wave & 1;
    int q = lane >> 4, lm = lane & 15;

    floatx4 acc1[4][4] = {};
    floatx4 acc3[4][4] = {};

    // Per-wave staging: 2 instrs per matrix per wave (64 lanes x 16B = 1KB
    // each; tile = 8KB). c = chunk index; row = c>>2; global chunk is the
    // inverse-swizzled (c&3) ^ ((row>>1)&3).
    const bf16* aG[2];
    const bf16* bG[2];
    int ldsOff[2];
#pragma unroll
    for (int it = 0; it < 2; ++it) {
        int c = wave * 128 + it * 64 + lane;
        int row = c >> 2;
        int g = (c & 3) ^ ((row >> 1) & 3);
        int rl = mt * 128 + row;
        int rr = rl < mcount ? rl : mcount - 1;
        long aoff;
        if (gather) aoff = (long)tok[rowbase + rr] * Dm;
        else        aoff = (long)rr * Dm;
        aG[it] = xb + aoff + g * 8;
        bG[it] = BT + (long)(ntile * 128 + row) * Dm + g * 8;
        ldsOff[it] = (wave * 128 + it * 64) * 8;   // linear dest, 128B/instr
    }

    auto stage = [&](int buf, int kt) {
#pragma unroll
        for (int it = 0; it < 2; ++it) {
            gload_lds16(aG[it] + (long)kt * 32,        &sm[buf][0][ldsOff[it]]);
            gload_lds16(bG[it] + (long)kt * 32,        &sm[buf][1][ldsOff[it]]);
            gload_lds16(bG[it] + off3 + (long)kt * 32, &sm[buf][2][ldsOff[it]]);
        }
    };

    stage(0, 0);
    for (int kt = 0; kt < Dm / 32; ++kt) {
        __syncthreads();                    // vmcnt(0): buf[kt&1] ready
        int cur = kt & 1;
        if (kt + 1 < Dm / 32) stage(cur ^ 1, kt + 1);   // prefetch in flight
        bf16x8 af[4], b1v[4], b3v[4];
#pragma unroll
        for (int i = 0; i < 4; ++i) {
            int row = wm * 64 + i * 16 + lm;
            af[i] = *(const bf16x8*)&sm[cur][0][row * 32 + ((q ^ ((row >> 1) & 3)) * 8)];
        }
#pragma unroll
        for (int j2 = 0; j2 < 4; ++j2) {
            int row = wn * 64 + j2 * 16 + lm;
            int sl = (q ^ ((row >> 1) & 3)) * 8;
            b1v[j2] = *(const bf16x8*)&sm[cur][1][row * 32 + sl];
            b3v[j2] = *(const bf16x8*)&sm[cur][2][row * 32 + sl];
        }
#pragma unroll
        for (int i = 0; i < 4; ++i)
#pragma unroll
            for (int j2 = 0; j2 < 4; ++j2) {
                acc1[i][j2] = __builtin_amdgcn_mfma_f32_16x16x32_bf16(
                    af[i], b1v[j2], acc1[i][j2], 0, 0, 0);
                acc3[i][j2] = __builtin_amdgcn_mfma_f32_16x16x32_bf16(
                    af[i], b3v[j2], acc3[i][j2], 0, 0, 0);
            }
    }

    int colbase = ntile * 128 + wn * 64;
#pragma unroll
    for (int i = 0; i < 4; ++i) {
        int rloc = wm * 64 + i * 16 + q * 4;
#pragma unroll
        for (int r = 0; r < 4; ++r) {
            int rl = mt * 128 + rloc + r;
            if (rl >= mcount) continue;
#pragma unroll
            for (int j2 = 0; j2 < 4; ++j2) {
                int col = colbase + j2 * 16 + lm;
                float a = acc1[i][j2][r], b = acc3[i][j2][r];
                float sg = 1.0f / (1.0f + __expf(-a));
                outH[(long)(rowbase + rl) * ldo + col] = (bf16)(a * sg * b);
            }
        }
    }
}

// Merged GEMM2: same R1-verified 2-phase pipeline. Flat 4352-block grid,
// XCD-chunked (lid = (bid&7)*544 + bid>>3). lid < 4096 -> routed (e=lid>>7,
// nt=(lid>>4)&7, mt=lid&15; A=Hh K=512, bf16 compact store to Yc); else
// shared (s=lid-4096, nt=s>>5, mt=s&31; A=HhS K=1024, fp32 store to out).
__global__ void __launch_bounds__(256, 2) gemm2_merged(
    const bf16* __restrict__ Hh, const bf16* __restrict__ HhS,
    const bf16* __restrict__ W2T, const bf16* __restrict__ Ws2T,
    const int* __restrict__ cntc, const int* __restrict__ offs,
    bf16* __restrict__ Yc, float* __restrict__ out)
{
    __shared__ __align__(16) bf16 sm[2][2][128 * 32];   // 32 KB (dbuf A,B)

    int bid = blockIdx.x;
    int lid = (bid & 7) * 544 + (bid >> 3);

    int mt, mcount, rowbase, K, lda, nt;
    const bf16* A;
    const bf16* BT;
    bool toBf;
    if (lid < 4096) {
        int e = lid >> 7;
        nt = (lid >> 4) & 7;
        mt = lid & 15;
        mcount = cntc[e];
        if (mt * 128 >= mcount) return;
        rowbase = offs[e];
        A = Hh; lda = Hm; K = Hm;
        BT = W2T + (long)e * Hm * Dm;
        toBf = true;
    } else {
        int s = lid - 4096;            // 256 shared blocks: 8 nt x 32 mt
        nt = s >> 5;
        mt = s & 31;
        mcount = T_TOK; rowbase = 0;
        A = HhS; lda = HsDim; K = HsDim;
        BT = Ws2T;
        toBf = false;
    }

    int tid = threadIdx.x;
    int wave = tid >> 6, lane = tid & 63;
    int wm = wave >> 1, wn = wave & 1;
    int q = lane >> 4, lm = lane & 15;

    floatx4 acc[4][4] = {};

    const bf16* aG[2];
    const bf16* bG[2];
    int ldsOff[2];
#pragma unroll
    for (int it = 0; it < 2; ++it) {
        int c = wave * 128 + it * 64 + lane;
        int row = c >> 2;
        int g = (c & 3) ^ ((row >> 1) & 3);
        int rl = mt * 128 + row;
        int rr = rl < mcount ? rl : mcount - 1;
        aG[it] = A + (long)(rowbase + rr) * lda + g * 8;
        bG[it] = BT + (long)(nt * 128 + row) * K + g * 8;
        ldsOff[it] = (wave * 128 + it * 64) * 8;
    }

    auto stage = [&](int buf, int kt) {
#pragma unroll
        for (int it = 0; it < 2; ++it) {
            gload_lds16(aG[it] + (long)kt * 32, &sm[buf][0][ldsOff[it]]);
            gload_lds16(bG[it] + (long)kt * 32, &sm[buf][1][ldsOff[it]]);
        }
    };

    int NT = K / 32;
    stage(0, 0);
    for (int kt = 0; kt < NT; ++kt) {
        __syncthreads();
        int cur = kt & 1;
        if (kt + 1 < NT) stage(cur ^ 1, kt + 1);
        bf16x8 af[4], bfv[4];
#pragma unroll
        for (int i = 0; i < 4; ++i) {
            int row = wm * 64 + i * 16 + lm;
            af[i] = *(const bf16x8*)&sm[cur][0][row * 32 + ((q ^ ((row >> 1) & 3)) * 8)];
        }
#pragma unroll
        for (int j2 = 0; j2 < 4; ++j2) {
            int row = wn * 64 + j2 * 16 + lm;
            bfv[j2] = *(const bf16x8*)&sm[cur][1][row * 32 + ((q ^ ((row >> 1) & 3)) * 8)];
        }
#pragma unroll
        for (int i = 0; i < 4; ++i)
#pragma unroll
            for (int j2 = 0; j2 < 4; ++j2)
                acc[i][j2] = __builtin_amdgcn_mfma_f32_16x16x32_bf16(
                    af[i], bfv[j2], acc[i][j2], 0, 0, 0);
    }

    int colbase = nt * 128 + wn * 64;
#pragma unroll
    for (int i = 0; i < 4; ++i) {
        int rloc = wm * 64 + i * 16 + q * 4;
#pragma unroll
        for (int r = 0; r < 4; ++r) {
            int rl = mt * 128 + rloc + r;
            if (rl >= mcount) continue;
#pragma unroll
            for (int j2 = 0; j2 < 4; ++j2) {
                int col = colbase + j2 * 16 + lm;
                float v = acc[i][j2][r];
                if (toBf) Yc[(long)(rowbase + rl) * Dm + col] = (bf16)v;
                else      out[(long)rl * Dm + col] = v;
            }
        }
    }
}

// ------------------------------------------------------------- combine ------
// out[t][:] += sum_k w[t,k] * Yc[posC[t*4+k]][:]  (posC<0 => dropped pair).
__global__ __launch_bounds__(256) void combine_kernel(
    const bf16* __restrict__ Yc, const float* __restrict__ topkW,
    const int* __restrict__ posC, float* __restrict__ out)
{
    __shared__ int   sp[4];
    __shared__ float sw[4];
    int t = blockIdx.x, tid = threadIdx.x;
    if (tid < 4) {
        sp[tid] = posC[t * 4 + tid];
        sw[tid] = topkW[t * 4 + tid];
    }
    __syncthreads();
    int d = tid * 4;
    float4 o = *(float4*)(out + (size_t)t * Dm + d);
#pragma unroll
    for (int k = 0; k < 4; ++k) {
        int rc = sp[k];
        if (rc >= 0) {
            bf16x4 v = *(const bf16x4*)(Yc + (size_t)rc * Dm + d);
            float w = sw[k];
            o.x += w * (float)v[0];
            o.y += w * (float)v[1];
            o.z += w * (float)v[2];
            o.w += w * (float)v[3];
        }
    }
    *(float4*)(out + (size_t)t * Dm + d) = o;
}

// ---------------------------------------------------------------- launch ----
extern "C" void kernel_launch(void* const* d_in, const int* in_sizes, int n_in,
                              void* d_out, int out_size, void* d_ws, size_t ws_size,
                              hipStream_t stream)
{
    const float* x   = (const float*)d_in[0];
    const float* Wg  = (const float*)d_in[1];
    const float* W1  = (const float*)d_in[2];
    const float* W2  = (const float*)d_in[3];
    const float* W3  = (const float*)d_in[4];
    const float* Ws1 = (const float*)d_in[5];
    const float* Ws2 = (const float*)d_in[6];
    const float* Ws3 = (const float*)d_in[7];
    float* out = (float*)d_out;

    char* p = (char*)d_ws;
    auto alloc = [&](size_t bytes) {
        char* r = p; p += (bytes + 255) & ~(size_t)255; return r;
    };
    bf16*  xb    = (bf16*)alloc((size_t)T_TOK * Dm * 2);
    bf16*  W13T  = (bf16*)alloc((size_t)Em * 2 * Hm * Dm * 2);
    bf16*  W2T   = (bf16*)alloc((size_t)Em * Dm * Hm * 2);
    bf16*  Ws13T = (bf16*)alloc((size_t)2 * HsDim * Dm * 2);
    bf16*  Ws2T  = (bf16*)alloc((size_t)Dm * HsDim * 2);
    bf16*  Yc    = (bf16*)alloc((size_t)Pp * Dm * 2);      // expert GEMM2 compact out
    bf16*  Hh    = (bf16*)alloc((size_t)Pp * Hm * 2);      // expert hidden (compact)
    bf16*  HhS   = (bf16*)alloc((size_t)T_TOK * HsDim * 2);// shared hidden
    float* logits= (float*)alloc((size_t)T_TOK * Em * 4);
    int*   topkE = (int*)alloc(Pp * 4);
    float* topkW = (float*)alloc(Pp * 4);
    int*   tokC  = (int*)alloc(Pp * 4);
    float* wtC   = (float*)alloc(Pp * 4);
    int*   posC  = (int*)alloc(Pp * 4);
    int*   cnt   = (int*)alloc(128);
    int*   cnt2  = (int*)alloc(128);
    int*   cntc  = (int*)alloc(128);
    int*   offs  = (int*)alloc(256);

    size_t need = (size_t)(p - (char*)d_ws);
    if (ws_size < need) {
        fprintf(stderr, "kernel_launch: ws too small (%zu < %zu)\n", ws_size, need);
        return;
    }

    hipMemsetAsync(cnt, 0, 1024, stream);  // cnt, cnt2, cntc, offs

    // Routing (fp32, matches reference top-k exactly) + x bf16 cast
    gate_logits<<<T_TOK / 8, 256, 0, stream>>>(x, Wg, logits, xb);
    gate_topk<<<T_TOK / 256, 256, 0, stream>>>(logits, topkE, topkW, cnt);
    offsets_kernel<<<1, 64, 0, stream>>>(cnt, cntc, offs);
    scatter_kernel<<<Pp / 256, 256, 0, stream>>>(topkE, topkW, cntc, offs, cnt2,
                                                 tokC, wtC, posC);

    // weight transposes+casts (3 dispatches)
    transpose_w13<<<dim3(Hm / 64, Dm / 64, 2 * Em), dim3(64, 4), 0, stream>>>(W1, W3, W13T);
    transpose_w2 <<<dim3(Dm / 64, Hm / 64, Em),     dim3(64, 4), 0, stream>>>(W2, W2T);
    transpose_ws <<<dim3(Dm / 64, Dm / 64, 3),      dim3(64, 4), 0, stream>>>(
        Ws1, Ws3, Ws2, Ws13T, Ws2T);

    // GEMM1 (both paths, fused SwiGLU) -> GEMM2 (both paths) -> combine
    gemm1_merged<<<dim3(2304), 256, 0, stream>>>(
        xb, W13T, Ws13T, cntc, offs, tokC, Hh, HhS);
    gemm2_merged<<<dim3(4352), 256, 0, stream>>>(
        Hh, HhS, W2T, Ws2T, cntc, offs, Yc, out);
    combine_kernel<<<T_TOK, 256, 0, stream>>>(Yc, topkW, posC, out);
}

// Round 5
// 437.606 us; speedup vs baseline: 1.2345x; 1.2240x over previous
//
#include <hip/hip_runtime.h>
#include <cstdio>

typedef __bf16 bf16;
typedef __bf16 bf16x8 __attribute__((ext_vector_type(8)));
typedef __bf16 bf16x4 __attribute__((ext_vector_type(4)));
typedef float floatx4 __attribute__((ext_vector_type(4)));

#define T_TOK 4096
#define Dm    1024
#define Hm    512
#define Em    32
#define HsDim 1024   // shared inter dim
#define Pp    16384  // T*K pairs
#define CAP   2048   // per-expert capacity

// ---------------------------------------------------------------- gate ------
// logits[t][e] = x[t][:] . Wg[:][e] in fp32 (must match reference routing).
// 8 tokens/block; also writes the bf16 cast of x (x rows already in LDS).
__global__ __launch_bounds__(256) void gate_logits(
    const float* __restrict__ xf, const float* __restrict__ Wg,
    float* __restrict__ logits, bf16* __restrict__ xb)
{
    __shared__ float xs[8][Dm];        // 32 KB
    __shared__ float wsC[128 * Em];    // 16 KB, natural [d][e] layout
    int tid = threadIdx.x;
    int t0 = blockIdx.x * 8;

    const float4* src = (const float4*)(xf + (size_t)t0 * Dm);
    float4* dst = (float4*)&xs[0][0];
#pragma unroll
    for (int i = 0; i < 8; ++i) dst[tid + i * 256] = src[tid + i * 256];

    int tg = tid >> 5, e = tid & 31;
    float acc = 0.f;
    for (int d0 = 0; d0 < Dm; d0 += 128) {
        __syncthreads();               // covers xs on iter 0, wsC reuse after
        const float4* wg4 = (const float4*)(Wg + (size_t)d0 * Em);
        float4* ws4 = (float4*)wsC;
#pragma unroll
        for (int i = 0; i < 4; ++i) ws4[tid + i * 256] = wg4[tid + i * 256];
        __syncthreads();
#pragma unroll
        for (int d = 0; d < 128; d += 4) {
            float4 xv = *(const float4*)&xs[tg][d0 + d];
            acc = fmaf(xv.x, wsC[(d + 0) * Em + e], acc);
            acc = fmaf(xv.y, wsC[(d + 1) * Em + e], acc);
            acc = fmaf(xv.z, wsC[(d + 2) * Em + e], acc);
            acc = fmaf(xv.w, wsC[(d + 3) * Em + e], acc);
        }
    }
    logits[(size_t)(t0 + tg) * Em + e] = acc;

    // bf16 cast of the 8 staged rows (xs unchanged since load; already synced)
    bf16x4* xbrow = (bf16x4*)(xb + (size_t)t0 * Dm);
    const float4* xsf = (const float4*)&xs[0][0];
#pragma unroll
    for (int i = 0; i < 8; ++i) {
        int idx = tid + i * 256;
        float4 v = xsf[idx];
        bf16x4 o = {(bf16)v.x, (bf16)v.y, (bf16)v.z, (bf16)v.w};
        xbrow[idx] = o;
    }
}

// Per-token softmax + stable top-4 (ties -> lower index, same as lax.top_k).
__global__ __launch_bounds__(256) void gate_topk(
    const float* __restrict__ logits, int* __restrict__ topk_e,
    float* __restrict__ topk_w, int* __restrict__ cnt)
{
    __shared__ int hist[Em];
    int tid = threadIdx.x;
    if (tid < Em) hist[tid] = 0;
    __syncthreads();

    int t = blockIdx.x * 256 + tid;
    float l[Em];
    float M = -3.0e38f;
#pragma unroll
    for (int i = 0; i < 8; ++i) {
        float4 v = *(const float4*)(logits + (size_t)t * Em + i * 4);
        l[i * 4 + 0] = v.x; l[i * 4 + 1] = v.y;
        l[i * 4 + 2] = v.z; l[i * 4 + 3] = v.w;
        M = fmaxf(M, fmaxf(fmaxf(v.x, v.y), fmaxf(v.z, v.w)));
    }
    float sum = 0.f;
#pragma unroll
    for (int i = 0; i < Em; ++i) sum += __expf(l[i] - M);
    float inv = 1.0f / sum;
#pragma unroll
    for (int k = 0; k < 4; ++k) {
        float best = -3.0e38f; int bi = 0;
#pragma unroll
        for (int i = 0; i < Em; ++i)
            if (l[i] > best) { best = l[i]; bi = i; }
        topk_e[t * 4 + k] = bi;
        topk_w[t * 4 + k] = __expf(best - M) * inv;
        atomicAdd(&hist[bi], 1);
#pragma unroll
        for (int i = 0; i < Em; ++i)
            if (i == bi) l[i] = -3.0e38f;
    }
    __syncthreads();
    if (tid < Em) { int h = hist[tid]; if (h) atomicAdd(&cnt[tid], h); }
}

__global__ void offsets_kernel(const int* __restrict__ cnt, int* __restrict__ cntc,
                               int* __restrict__ offs)
{
    if (threadIdx.x == 0) {
        int run = 0;
        for (int e = 0; e < Em; ++e) {
            int c = cnt[e]; if (c > CAP) c = CAP;
            cntc[e] = c; offs[e] = run; run += c;
        }
        offs[Em] = run;
    }
}

// Records pair -> compact-row map (posC, -1 = capacity-dropped).
__global__ void scatter_kernel(const int* __restrict__ topk_e, const float* __restrict__ topk_w,
                               const int* __restrict__ cntc, const int* __restrict__ offs,
                               int* __restrict__ cnt2, int* __restrict__ tok_c,
                               float* __restrict__ wt_c, int* __restrict__ posC)
{
    int p = blockIdx.x * 256 + threadIdx.x;
    if (p >= Pp) return;
    int e = topk_e[p];
    int slot = atomicAdd(&cnt2[e], 1);
    int rc = -1;
    if (slot < cntc[e]) {
        rc = offs[e] + slot;
        tok_c[rc] = p >> 2;
        wt_c[rc] = topk_w[p];
    }
    posC[p] = rc;
}

// ---------------------------------------------------------------- casts -----
// 64x64 tile fp32->bf16 transpose. Block (64,4). Reads 256B/wave contiguous;
// LDS reads 2-way aliased (free per m136).
__device__ __forceinline__ void transpose_tile64(
    const float* __restrict__ src, bf16* __restrict__ dst, int R, int Cc)
{
    __shared__ float t[64][65];
    int r0 = blockIdx.y * 64, c0 = blockIdx.x * 64;
    int tx = threadIdx.x, ty = threadIdx.y;
#pragma unroll
    for (int i = 0; i < 16; ++i) {
        int row = ty + i * 4;
        t[row][tx] = src[(long)(r0 + row) * Cc + (c0 + tx)];
    }
    __syncthreads();
#pragma unroll
    for (int i = 0; i < 16; ++i) {
        int row = ty + i * 4;
        dst[(long)(c0 + row) * R + (r0 + tx)] = (bf16)t[tx][row];
    }
}

// W1 (z<32) and W3 (z>=32): (Dm x Hm) -> rows [0,512) / [512,1024) of the
// per-expert 1024 x Dm block of W13T.
__global__ __launch_bounds__(256) void transpose_w13(
    const float* __restrict__ W1, const float* __restrict__ W3,
    bf16* __restrict__ W13T)
{
    int z = blockIdx.z;
    int e = z & 31;
    const float* src = (z < 32 ? W1 : W3) + (long)e * Dm * Hm;
    bf16* dst = W13T + (long)e * 2 * Hm * Dm + (z < 32 ? 0 : (long)Hm * Dm);
    transpose_tile64(src, dst, Dm, Hm);
}

// W2[e]: (Hm x Dm) -> (Dm x Hm)
__global__ __launch_bounds__(256) void transpose_w2(
    const float* __restrict__ W2, bf16* __restrict__ W2T)
{
    int e = blockIdx.z;
    transpose_tile64(W2 + (long)e * Hm * Dm, W2T + (long)e * Hm * Dm, Hm, Dm);
}

// Ws1 / Ws3 / Ws2, each (1024 x 1024), selected by z.
__global__ __launch_bounds__(256) void transpose_ws(
    const float* __restrict__ Ws1, const float* __restrict__ Ws3,
    const float* __restrict__ Ws2, bf16* __restrict__ Ws13T,
    bf16* __restrict__ Ws2T)
{
    int z = blockIdx.z;
    const float* src = z == 0 ? Ws1 : (z == 1 ? Ws3 : Ws2);
    bf16* dst = z == 0 ? Ws13T : (z == 1 ? Ws13T + (long)HsDim * Dm : Ws2T);
    transpose_tile64(src, dst, Dm, Dm);
}

// ---------------------------------------------------------------- GEMM ------
// 128x128 tile, BK=32, 4 waves (64x64 each), mfma_f32_16x16x32_bf16.
// R1-verified 2-phase double-buffered pipeline (105 us gemm1): prefetch for
// tile kt+1 issued immediately after __syncthreads, so the vmcnt(0) drain in
// the NEXT barrier lands after a full ds_read+MFMA phase. Compiler-scheduled
// (no sched_barrier pinning — m141/R3 regression), 48 KB LDS (3 blocks/CU).
//
// Swizzle (BK=32, 64B rows, 4x 16B chunks/row): LDS slot for chunk q of row
// r is q ^ ((r>>1)&3); inverse permutation applied to the per-lane GLOBAL
// address (LDS dest stays linear, as global_load_lds requires).
__device__ __forceinline__ void gload_lds16(const bf16* g, bf16* l)
{
    __builtin_amdgcn_global_load_lds((const __attribute__((address_space(1))) void*)g,
                                     (__attribute__((address_space(3))) void*)l, 16, 0, 0);
}

// Merged GEMM1 (+fused SwiGLU), flat 2304-block grid with BALANCED
// XCD-chunked decode (R4 post-mortem: naive chunking put ALL 256 shared
// blocks on XCD 7 -> 7/8 XCDs idle in the tail; occupancy 11.2->7.5).
// XCD i = bid&7 (round-robin dispatch assumption; perf-only), rank
// r = bid>>3 in [0,288):
//   r < 256  -> routed: e = 4i + (r>>6) (4 experts/XCD, B-panels L2-local),
//               ntile = (r>>4)&3, mt = r&15 (same-panel blocks consecutive).
//   r >= 256 -> shared: mt = 4i + ((r-256)>>3), ntile = (r-256)&7
//               (each XCD: 4 m-tiles x all 8 n-tiles; B 4MB = L2-resident,
//                shared work split 8 ways exactly).
// R4 evidence the locality mechanism works: FETCH_SIZE 137 -> 70 MB.
__global__ void __launch_bounds__(256, 2) gemm1_merged(
    const bf16* __restrict__ xb, const bf16* __restrict__ W13T,
    const bf16* __restrict__ Ws13T,
    const int* __restrict__ cntc, const int* __restrict__ offs,
    const int* __restrict__ tok,
    bf16* __restrict__ Hh, bf16* __restrict__ HhS)
{
    __shared__ __align__(16) bf16 sm[2][3][128 * 32];   // 48 KB (dbuf A,B1,B3)

    int bid = blockIdx.x;
    int xcd = bid & 7, rk = bid >> 3;   // rk in [0,288)

    int mt, mcount, rowbase, ntile;
    const bf16* BT;
    bf16* outH;
    int ldo;
    long off3;
    bool gather;
    if (rk < 256) {
        int e = xcd * 4 + (rk >> 6);
        ntile = (rk >> 4) & 3;
        mt = rk & 15;
        mcount = cntc[e];
        if (mt * 128 >= mcount) return;
        rowbase = offs[e];
        BT = W13T + (long)e * 2 * Hm * Dm;
        outH = Hh; ldo = Hm; off3 = (long)Hm * Dm;
        gather = true;
    } else {
        int s = rk - 256;              // [0,32): 4 mt x 8 nt per XCD
        mt = xcd * 4 + (s >> 3);
        ntile = s & 7;
        mcount = T_TOK; rowbase = 0;
        BT = Ws13T;
        outH = HhS; ldo = HsDim; off3 = (long)HsDim * Dm;
        gather = false;
    }

    int tid = threadIdx.x;
    int wave = tid >> 6, lane = tid & 63;
    int wm = wave >> 1, wn = wave & 1;
    int q = lane >> 4, lm = lane & 15;

    floatx4 acc1[4][4] = {};
    floatx4 acc3[4][4] = {};

    // Per-wave staging: 2 instrs per matrix per wave (64 lanes x 16B = 1KB
    // each; tile = 8KB). c = chunk index; row = c>>2; global chunk is the
    // inverse-swizzled (c&3) ^ ((row>>1)&3).
    const bf16* aG[2];
    const bf16* bG[2];
    int ldsOff[2];
#pragma unroll
    for (int it = 0; it < 2; ++it) {
        int c = wave * 128 + it * 64 + lane;
        int row = c >> 2;
        int g = (c & 3) ^ ((row >> 1) & 3);
        int rl = mt * 128 + row;
        int rr = rl < mcount ? rl : mcount - 1;
        long aoff;
        if (gather) aoff = (long)tok[rowbase + rr] * Dm;
        else        aoff = (long)rr * Dm;
        aG[it] = xb + aoff + g * 8;
        bG[it] = BT + (long)(ntile * 128 + row) * Dm + g * 8;
        ldsOff[it] = (wave * 128 + it * 64) * 8;   // linear dest, 128B/instr
    }

    auto stage = [&](int buf, int kt) {
#pragma unroll
        for (int it = 0; it < 2; ++it) {
            gload_lds16(aG[it] + (long)kt * 32,        &sm[buf][0][ldsOff[it]]);
            gload_lds16(bG[it] + (long)kt * 32,        &sm[buf][1][ldsOff[it]]);
            gload_lds16(bG[it] + off3 + (long)kt * 32, &sm[buf][2][ldsOff[it]]);
        }
    };

    stage(0, 0);
    for (int kt = 0; kt < Dm / 32; ++kt) {
        __syncthreads();                    // vmcnt(0): buf[kt&1] ready
        int cur = kt & 1;
        if (kt + 1 < Dm / 32) stage(cur ^ 1, kt + 1);   // prefetch in flight
        bf16x8 af[4], b1v[4], b3v[4];
#pragma unroll
        for (int i = 0; i < 4; ++i) {
            int row = wm * 64 + i * 16 + lm;
            af[i] = *(const bf16x8*)&sm[cur][0][row * 32 + ((q ^ ((row >> 1) & 3)) * 8)];
        }
#pragma unroll
        for (int j2 = 0; j2 < 4; ++j2) {
            int row = wn * 64 + j2 * 16 + lm;
            int sl = (q ^ ((row >> 1) & 3)) * 8;
            b1v[j2] = *(const bf16x8*)&sm[cur][1][row * 32 + sl];
            b3v[j2] = *(const bf16x8*)&sm[cur][2][row * 32 + sl];
        }
#pragma unroll
        for (int i = 0; i < 4; ++i)
#pragma unroll
            for (int j2 = 0; j2 < 4; ++j2) {
                acc1[i][j2] = __builtin_amdgcn_mfma_f32_16x16x32_bf16(
                    af[i], b1v[j2], acc1[i][j2], 0, 0, 0);
                acc3[i][j2] = __builtin_amdgcn_mfma_f32_16x16x32_bf16(
                    af[i], b3v[j2], acc3[i][j2], 0, 0, 0);
            }
    }

    int colbase = ntile * 128 + wn * 64;
#pragma unroll
    for (int i = 0; i < 4; ++i) {
        int rloc = wm * 64 + i * 16 + q * 4;
#pragma unroll
        for (int r = 0; r < 4; ++r) {
            int rl = mt * 128 + rloc + r;
            if (rl >= mcount) continue;
#pragma unroll
            for (int j2 = 0; j2 < 4; ++j2) {
                int col = colbase + j2 * 16 + lm;
                float a = acc1[i][j2][r], b = acc3[i][j2][r];
                float sg = 1.0f / (1.0f + __expf(-a));
                outH[(long)(rowbase + rl) * ldo + col] = (bf16)(a * sg * b);
            }
        }
    }
}

// Merged GEMM2: same R1-verified 2-phase pipeline. Flat 4352-block grid,
// BALANCED XCD-chunked decode: XCD i = bid&7, rank r = bid>>3 in [0,544):
//   r < 512  -> routed: e = 4i + (r>>7), nt = (r>>4)&7, mt = r&15
//               (A=Hh K=512, bf16 compact store to Yc)
//   r >= 512 -> shared: mt = 4i + ((r-512)>>3), nt = (r-512)&7
//               (A=HhS K=1024, fp32 store to out)
__global__ void __launch_bounds__(256, 2) gemm2_merged(
    const bf16* __restrict__ Hh, const bf16* __restrict__ HhS,
    const bf16* __restrict__ W2T, const bf16* __restrict__ Ws2T,
    const int* __restrict__ cntc, const int* __restrict__ offs,
    bf16* __restrict__ Yc, float* __restrict__ out)
{
    __shared__ __align__(16) bf16 sm[2][2][128 * 32];   // 32 KB (dbuf A,B)

    int bid = blockIdx.x;
    int xcd = bid & 7, rk = bid >> 3;   // rk in [0,544)

    int mt, mcount, rowbase, K, lda, nt;
    const bf16* A;
    const bf16* BT;
    bool toBf;
    if (rk < 512) {
        int e = xcd * 4 + (rk >> 7);
        nt = (rk >> 4) & 7;
        mt = rk & 15;
        mcount = cntc[e];
        if (mt * 128 >= mcount) return;
        rowbase = offs[e];
        A = Hh; lda = Hm; K = Hm;
        BT = W2T + (long)e * Hm * Dm;
        toBf = true;
    } else {
        int s = rk - 512;              // [0,32): 4 mt x 8 nt per XCD
        mt = xcd * 4 + (s >> 3);
        nt = s & 7;
        mcount = T_TOK; rowbase = 0;
        A = HhS; lda = HsDim; K = HsDim;
        BT = Ws2T;
        toBf = false;
    }

    int tid = threadIdx.x;
    int wave = tid >> 6, lane = tid & 63;
    int wm = wave >> 1, wn = wave & 1;
    int q = lane >> 4, lm = lane & 15;

    floatx4 acc[4][4] = {};

    const bf16* aG[2];
    const bf16* bG[2];
    int ldsOff[2];
#pragma unroll
    for (int it = 0; it < 2; ++it) {
        int c = wave * 128 + it * 64 + lane;
        int row = c >> 2;
        int g = (c & 3) ^ ((row >> 1) & 3);
        int rl = mt * 128 + row;
        int rr = rl < mcount ? rl : mcount - 1;
        aG[it] = A + (long)(rowbase + rr) * lda + g * 8;
        bG[it] = BT + (long)(nt * 128 + row) * K + g * 8;
        ldsOff[it] = (wave * 128 + it * 64) * 8;
    }

    auto stage = [&](int buf, int kt) {
#pragma unroll
        for (int it = 0; it < 2; ++it) {
            gload_lds16(aG[it] + (long)kt * 32, &sm[buf][0][ldsOff[it]]);
            gload_lds16(bG[it] + (long)kt * 32, &sm[buf][1][ldsOff[it]]);
        }
    };

    int NT = K / 32;
    stage(0, 0);
    for (int kt = 0; kt < NT; ++kt) {
        __syncthreads();
        int cur = kt & 1;
        if (kt + 1 < NT) stage(cur ^ 1, kt + 1);
        bf16x8 af[4], bfv[4];
#pragma unroll
        for (int i = 0; i < 4; ++i) {
            int row = wm * 64 + i * 16 + lm;
            af[i] = *(const bf16x8*)&sm[cur][0][row * 32 + ((q ^ ((row >> 1) & 3)) * 8)];
        }
#pragma unroll
        for (int j2 = 0; j2 < 4; ++j2) {
            int row = wn * 64 + j2 * 16 + lm;
            bfv[j2] = *(const bf16x8*)&sm[cur][1][row * 32 + ((q ^ ((row >> 1) & 3)) * 8)];
        }
#pragma unroll
        for (int i = 0; i < 4; ++i)
#pragma unroll
            for (int j2 = 0; j2 < 4; ++j2)
                acc[i][j2] = __builtin_amdgcn_mfma_f32_16x16x32_bf16(
                    af[i], bfv[j2], acc[i][j2], 0, 0, 0);
    }

    int colbase = nt * 128 + wn * 64;
#pragma unroll
    for (int i = 0; i < 4; ++i) {
        int rloc = wm * 64 + i * 16 + q * 4;
#pragma unroll
        for (int r = 0; r < 4; ++r) {
            int rl = mt * 128 + rloc + r;
            if (rl >= mcount) continue;
#pragma unroll
            for (int j2 = 0; j2 < 4; ++j2) {
                int col = colbase + j2 * 16 + lm;
                float v = acc[i][j2][r];
                if (toBf) Yc[(long)(rowbase + rl) * Dm + col] = (bf16)v;
                else      out[(long)rl * Dm + col] = v;
            }
        }
    }
}

// ------------------------------------------------------------- combine ------
// out[t][:] += sum_k w[t,k] * Yc[posC[t*4+k]][:]  (posC<0 => dropped pair).
__global__ __launch_bounds__(256) void combine_kernel(
    const bf16* __restrict__ Yc, const float* __restrict__ topkW,
    const int* __restrict__ posC, float* __restrict__ out)
{
    __shared__ int   sp[4];
    __shared__ float sw[4];
    int t = blockIdx.x, tid = threadIdx.x;
    if (tid < 4) {
        sp[tid] = posC[t * 4 + tid];
        sw[tid] = topkW[t * 4 + tid];
    }
    __syncthreads();
    int d = tid * 4;
    float4 o = *(float4*)(out + (size_t)t * Dm + d);
#pragma unroll
    for (int k = 0; k < 4; ++k) {
        int rc = sp[k];
        if (rc >= 0) {
            bf16x4 v = *(const bf16x4*)(Yc + (size_t)rc * Dm + d);
            float w = sw[k];
            o.x += w * (float)v[0];
            o.y += w * (float)v[1];
            o.z += w * (float)v[2];
            o.w += w * (float)v[3];
        }
    }
    *(float4*)(out + (size_t)t * Dm + d) = o;
}

// ---------------------------------------------------------------- launch ----
extern "C" void kernel_launch(void* const* d_in, const int* in_sizes, int n_in,
                              void* d_out, int out_size, void* d_ws, size_t ws_size,
                              hipStream_t stream)
{
    const float* x   = (const float*)d_in[0];
    const float* Wg  = (const float*)d_in[1];
    const float* W1  = (const float*)d_in[2];
    const float* W2  = (const float*)d_in[3];
    const float* W3  = (const float*)d_in[4];
    const float* Ws1 = (const float*)d_in[5];
    const float* Ws2 = (const float*)d_in[6];
    const float* Ws3 = (const float*)d_in[7];
    float* out = (float*)d_out;

    char* p = (char*)d_ws;
    auto alloc = [&](size_t bytes) {
        char* r = p; p += (bytes + 255) & ~(size_t)255; return r;
    };
    bf16*  xb    = (bf16*)alloc((size_t)T_TOK * Dm * 2);
    bf16*  W13T  = (bf16*)alloc((size_t)Em * 2 * Hm * Dm * 2);
    bf16*  W2T   = (bf16*)alloc((size_t)Em * Dm * Hm * 2);
    bf16*  Ws13T = (bf16*)alloc((size_t)2 * HsDim * Dm * 2);
    bf16*  Ws2T  = (bf16*)alloc((size_t)Dm * HsDim * 2);
    bf16*  Yc    = (bf16*)alloc((size_t)Pp * Dm * 2);      // expert GEMM2 compact out
    bf16*  Hh    = (bf16*)alloc((size_t)Pp * Hm * 2);      // expert hidden (compact)
    bf16*  HhS   = (bf16*)alloc((size_t)T_TOK * HsDim * 2);// shared hidden
    float* logits= (float*)alloc((size_t)T_TOK * Em * 4);
    int*   topkE = (int*)alloc(Pp * 4);
    float* topkW = (float*)alloc(Pp * 4);
    int*   tokC  = (int*)alloc(Pp * 4);
    float* wtC   = (float*)alloc(Pp * 4);
    int*   posC  = (int*)alloc(Pp * 4);
    int*   cnt   = (int*)alloc(128);
    int*   cnt2  = (int*)alloc(128);
    int*   cntc  = (int*)alloc(128);
    int*   offs  = (int*)alloc(256);

    size_t need = (size_t)(p - (char*)d_ws);
    if (ws_size < need) {
        fprintf(stderr, "kernel_launch: ws too small (%zu < %zu)\n", ws_size, need);
        return;
    }

    hipMemsetAsync(cnt, 0, 1024, stream);  // cnt, cnt2, cntc, offs

    // Routing (fp32, matches reference top-k exactly) + x bf16 cast
    gate_logits<<<T_TOK / 8, 256, 0, stream>>>(x, Wg, logits, xb);
    gate_topk<<<T_TOK / 256, 256, 0, stream>>>(logits, topkE, topkW, cnt);
    offsets_kernel<<<1, 64, 0, stream>>>(cnt, cntc, offs);
    scatter_kernel<<<Pp / 256, 256, 0, stream>>>(topkE, topkW, cntc, offs, cnt2,
                                                 tokC, wtC, posC);

    // weight transposes+casts (3 dispatches)
    transpose_w13<<<dim3(Hm / 64, Dm / 64, 2 * Em), dim3(64, 4), 0, stream>>>(W1, W3, W13T);
    transpose_w2 <<<dim3(Dm / 64, Hm / 64, Em),     dim3(64, 4), 0, stream>>>(W2, W2T);
    transpose_ws <<<dim3(Dm / 64, Dm / 64, 3),      dim3(64, 4), 0, stream>>>(
        Ws1, Ws3, Ws2, Ws13T, Ws2T);

    // GEMM1 (both paths, fused SwiGLU) -> GEMM2 (both paths) -> combine
    gemm1_merged<<<dim3(2304), 256, 0, stream>>>(
        xb, W13T, Ws13T, cntc, offs, tokC, Hh, HhS);
    gemm2_merged<<<dim3(4352), 256, 0, stream>>>(
        Hh, HhS, W2T, Ws2T, cntc, offs, Yc, out);
    combine_kernel<<<T_TOK, 256, 0, stream>>>(Yc, topkW, posC, out);
}

// Round 6
// 436.199 us; speedup vs baseline: 1.2385x; 1.0032x over previous
//
#include <hip/hip_runtime.h>
#include <cstdio>

typedef __bf16 bf16;
typedef __bf16 bf16x8 __attribute__((ext_vector_type(8)));
typedef __bf16 bf16x4 __attribute__((ext_vector_type(4)));
typedef float floatx4 __attribute__((ext_vector_type(4)));

#define T_TOK 4096
#define Dm    1024
#define Hm    512
#define Em    32
#define HsDim 1024   // shared inter dim
#define Pp    16384  // T*K pairs
#define CAP   2048   // per-expert capacity

// ---------------------------------------------------------------- gate ------
// logits[t][e] = x[t][:] . Wg[:][e] in fp32 (must match reference routing).
// 8 tokens/block; also writes the bf16 cast of x (x rows already in LDS).
__global__ __launch_bounds__(256) void gate_logits(
    const float* __restrict__ xf, const float* __restrict__ Wg,
    float* __restrict__ logits, bf16* __restrict__ xb)
{
    __shared__ float xs[8][Dm];        // 32 KB
    __shared__ float wsC[128 * Em];    // 16 KB, natural [d][e] layout
    int tid = threadIdx.x;
    int t0 = blockIdx.x * 8;

    const float4* src = (const float4*)(xf + (size_t)t0 * Dm);
    float4* dst = (float4*)&xs[0][0];
#pragma unroll
    for (int i = 0; i < 8; ++i) dst[tid + i * 256] = src[tid + i * 256];

    int tg = tid >> 5, e = tid & 31;
    float acc = 0.f;
    for (int d0 = 0; d0 < Dm; d0 += 128) {
        __syncthreads();               // covers xs on iter 0, wsC reuse after
        const float4* wg4 = (const float4*)(Wg + (size_t)d0 * Em);
        float4* ws4 = (float4*)wsC;
#pragma unroll
        for (int i = 0; i < 4; ++i) ws4[tid + i * 256] = wg4[tid + i * 256];
        __syncthreads();
#pragma unroll
        for (int d = 0; d < 128; d += 4) {
            float4 xv = *(const float4*)&xs[tg][d0 + d];
            acc = fmaf(xv.x, wsC[(d + 0) * Em + e], acc);
            acc = fmaf(xv.y, wsC[(d + 1) * Em + e], acc);
            acc = fmaf(xv.z, wsC[(d + 2) * Em + e], acc);
            acc = fmaf(xv.w, wsC[(d + 3) * Em + e], acc);
        }
    }
    logits[(size_t)(t0 + tg) * Em + e] = acc;

    // bf16 cast of the 8 staged rows (xs unchanged since load; already synced)
    bf16x4* xbrow = (bf16x4*)(xb + (size_t)t0 * Dm);
    const float4* xsf = (const float4*)&xs[0][0];
#pragma unroll
    for (int i = 0; i < 8; ++i) {
        int idx = tid + i * 256;
        float4 v = xsf[idx];
        bf16x4 o = {(bf16)v.x, (bf16)v.y, (bf16)v.z, (bf16)v.w};
        xbrow[idx] = o;
    }
}

// Per-token softmax + stable top-4 (ties -> lower index, same as lax.top_k).
__global__ __launch_bounds__(256) void gate_topk(
    const float* __restrict__ logits, int* __restrict__ topk_e,
    float* __restrict__ topk_w, int* __restrict__ cnt)
{
    __shared__ int hist[Em];
    int tid = threadIdx.x;
    if (tid < Em) hist[tid] = 0;
    __syncthreads();

    int t = blockIdx.x * 256 + tid;
    float l[Em];
    float M = -3.0e38f;
#pragma unroll
    for (int i = 0; i < 8; ++i) {
        float4 v = *(const float4*)(logits + (size_t)t * Em + i * 4);
        l[i * 4 + 0] = v.x; l[i * 4 + 1] = v.y;
        l[i * 4 + 2] = v.z; l[i * 4 + 3] = v.w;
        M = fmaxf(M, fmaxf(fmaxf(v.x, v.y), fmaxf(v.z, v.w)));
    }
    float sum = 0.f;
#pragma unroll
    for (int i = 0; i < Em; ++i) sum += __expf(l[i] - M);
    float inv = 1.0f / sum;
#pragma unroll
    for (int k = 0; k < 4; ++k) {
        float best = -3.0e38f; int bi = 0;
#pragma unroll
        for (int i = 0; i < Em; ++i)
            if (l[i] > best) { best = l[i]; bi = i; }
        topk_e[t * 4 + k] = bi;
        topk_w[t * 4 + k] = __expf(best - M) * inv;
        atomicAdd(&hist[bi], 1);
#pragma unroll
        for (int i = 0; i < Em; ++i)
            if (i == bi) l[i] = -3.0e38f;
    }
    __syncthreads();
    if (tid < Em) { int h = hist[tid]; if (h) atomicAdd(&cnt[tid], h); }
}

__global__ void offsets_kernel(const int* __restrict__ cnt, int* __restrict__ cntc,
                               int* __restrict__ offs)
{
    if (threadIdx.x == 0) {
        int run = 0;
        for (int e = 0; e < Em; ++e) {
            int c = cnt[e]; if (c > CAP) c = CAP;
            cntc[e] = c; offs[e] = run; run += c;
        }
        offs[Em] = run;
    }
}

// Records pair -> compact-row map (posC, -1 = capacity-dropped).
__global__ void scatter_kernel(const int* __restrict__ topk_e, const float* __restrict__ topk_w,
                               const int* __restrict__ cntc, const int* __restrict__ offs,
                               int* __restrict__ cnt2, int* __restrict__ tok_c,
                               float* __restrict__ wt_c, int* __restrict__ posC)
{
    int p = blockIdx.x * 256 + threadIdx.x;
    if (p >= Pp) return;
    int e = topk_e[p];
    int slot = atomicAdd(&cnt2[e], 1);
    int rc = -1;
    if (slot < cntc[e]) {
        rc = offs[e] + slot;
        tok_c[rc] = p >> 2;
        wt_c[rc] = topk_w[p];
    }
    posC[p] = rc;
}

// ---------------------------------------------------------------- casts -----
// 64x64 tile fp32->bf16 transpose. Block (64,4). Reads 256B/wave contiguous;
// LDS reads 2-way aliased (free per m136).
__device__ __forceinline__ void transpose_tile64(
    const float* __restrict__ src, bf16* __restrict__ dst, int R, int Cc)
{
    __shared__ float t[64][65];
    int r0 = blockIdx.y * 64, c0 = blockIdx.x * 64;
    int tx = threadIdx.x, ty = threadIdx.y;
#pragma unroll
    for (int i = 0; i < 16; ++i) {
        int row = ty + i * 4;
        t[row][tx] = src[(long)(r0 + row) * Cc + (c0 + tx)];
    }
    __syncthreads();
#pragma unroll
    for (int i = 0; i < 16; ++i) {
        int row = ty + i * 4;
        dst[(long)(c0 + row) * R + (r0 + tx)] = (bf16)t[tx][row];
    }
}

// W1 (z<32) and W3 (z>=32): (Dm x Hm) -> rows [0,512) / [512,1024) of the
// per-expert 1024 x Dm block of W13T.
__global__ __launch_bounds__(256) void transpose_w13(
    const float* __restrict__ W1, const float* __restrict__ W3,
    bf16* __restrict__ W13T)
{
    int z = blockIdx.z;
    int e = z & 31;
    const float* src = (z < 32 ? W1 : W3) + (long)e * Dm * Hm;
    bf16* dst = W13T + (long)e * 2 * Hm * Dm + (z < 32 ? 0 : (long)Hm * Dm);
    transpose_tile64(src, dst, Dm, Hm);
}

// W2[e]: (Hm x Dm) -> (Dm x Hm)
__global__ __launch_bounds__(256) void transpose_w2(
    const float* __restrict__ W2, bf16* __restrict__ W2T)
{
    int e = blockIdx.z;
    transpose_tile64(W2 + (long)e * Hm * Dm, W2T + (long)e * Hm * Dm, Hm, Dm);
}

// Ws1 / Ws3 / Ws2, each (1024 x 1024), selected by z.
__global__ __launch_bounds__(256) void transpose_ws(
    const float* __restrict__ Ws1, const float* __restrict__ Ws3,
    const float* __restrict__ Ws2, bf16* __restrict__ Ws13T,
    bf16* __restrict__ Ws2T)
{
    int z = blockIdx.z;
    const float* src = z == 0 ? Ws1 : (z == 1 ? Ws3 : Ws2);
    bf16* dst = z == 0 ? Ws13T : (z == 1 ? Ws13T + (long)HsDim * Dm : Ws2T);
    transpose_tile64(src, dst, Dm, Dm);
}

// ---------------------------------------------------------------- GEMM ------
// 128x128 tile, BK=32, 4 waves (64x64 each), mfma_f32_16x16x32_bf16.
// DEPTH-2 counted-vmcnt pipeline (T4), NO sched_barrier pinning (m141/R3
// regression), ONE barrier per K-step (same count as the verified R5 loop):
//   s_waitcnt vmcnt(S) lgkmcnt(0)   // own stage-kt loads retired; all my
//                                   // ds_reads done (race-close, rule #18)
//   s_barrier ("memory" clobber)    // everyone's stage-kt landed
//   stage(kt+2) into buf (kt+2)%3   // == buf kt-1, whose reads finished
//                                   // before this barrier (lgkmcnt above)
//   ds_read fragments + MFMA        // compiler-scheduled freely
// Stage kt+2 thus gets TWO full compute phases before its vmcnt wait ->
// covers HBM latency (~900cy, m126) that the 2-phase drain exposed.
// S = loads/stage/wave (6 for gemm1, 4 for gemm2); last iter waits vmcnt(0).
//
// Swizzle (BK=32, 64B rows, 4x 16B chunks/row): LDS slot for chunk q of row
// r is q ^ ((r>>1)&3); inverse permutation applied to the per-lane GLOBAL
// address (LDS dest stays linear, as global_load_lds requires).
__device__ __forceinline__ void gload_lds16(const bf16* g, bf16* l)
{
    __builtin_amdgcn_global_load_lds((const __attribute__((address_space(1))) void*)g,
                                     (__attribute__((address_space(3))) void*)l, 16, 0, 0);
}

// Merged GEMM1 (+fused SwiGLU), flat 2304-block grid with BALANCED
// XCD-chunked decode (R5-verified: FETCH 137->74 MB, dur 106->95 us).
// XCD i = bid&7, rank r = bid>>3 in [0,288):
//   r < 256  -> routed: e = 4i + (r>>6), ntile = (r>>4)&3, mt = r&15.
//   r >= 256 -> shared: mt = 4i + ((r-256)>>3), ntile = (r-256)&7.
__global__ void __launch_bounds__(256, 2) gemm1_merged(
    const bf16* __restrict__ xb, const bf16* __restrict__ W13T,
    const bf16* __restrict__ Ws13T,
    const int* __restrict__ cntc, const int* __restrict__ offs,
    const int* __restrict__ tok,
    bf16* __restrict__ Hh, bf16* __restrict__ HhS)
{
    __shared__ __align__(16) bf16 sm[3][3][128 * 32];   // 72 KB (3buf A,B1,B3)

    int bid = blockIdx.x;
    int xcd = bid & 7, rk = bid >> 3;   // rk in [0,288)

    int mt, mcount, rowbase, ntile;
    const bf16* BT;
    bf16* outH;
    int ldo;
    long off3;
    bool gather;
    if (rk < 256) {
        int e = xcd * 4 + (rk >> 6);
        ntile = (rk >> 4) & 3;
        mt = rk & 15;
        mcount = cntc[e];
        if (mt * 128 >= mcount) return;
        rowbase = offs[e];
        BT = W13T + (long)e * 2 * Hm * Dm;
        outH = Hh; ldo = Hm; off3 = (long)Hm * Dm;
        gather = true;
    } else {
        int s = rk - 256;              // [0,32): 4 mt x 8 nt per XCD
        mt = xcd * 4 + (s >> 3);
        ntile = s & 7;
        mcount = T_TOK; rowbase = 0;
        BT = Ws13T;
        outH = HhS; ldo = HsDim; off3 = (long)HsDim * Dm;
        gather = false;
    }

    int tid = threadIdx.x;
    int wave = tid >> 6, lane = tid & 63;
    int wm = wave >> 1, wn = wave & 1;
    int q = lane >> 4, lm = lane & 15;

    floatx4 acc1[4][4] = {};
    floatx4 acc3[4][4] = {};

    // Per-wave staging: 2 instrs per matrix per wave (64 lanes x 16B = 1KB
    // each; tile = 8KB). c = chunk index; row = c>>2; global chunk is the
    // inverse-swizzled (c&3) ^ ((row>>1)&3).
    const bf16* aG[2];
    const bf16* bG[2];
    int ldsOff[2];
#pragma unroll
    for (int it = 0; it < 2; ++it) {
        int c = wave * 128 + it * 64 + lane;
        int row = c >> 2;
        int g = (c & 3) ^ ((row >> 1) & 3);
        int rl = mt * 128 + row;
        int rr = rl < mcount ? rl : mcount - 1;
        long aoff;
        if (gather) aoff = (long)tok[rowbase + rr] * Dm;
        else        aoff = (long)rr * Dm;
        aG[it] = xb + aoff + g * 8;
        bG[it] = BT + (long)(ntile * 128 + row) * Dm + g * 8;
        ldsOff[it] = (wave * 128 + it * 64) * 8;   // linear dest, 128B/instr
    }

    // LDS fragment element-offsets (kt-invariant, swizzled)
    int aoffL[4], boffL[4];
#pragma unroll
    for (int i = 0; i < 4; ++i) {
        int ra = wm * 64 + i * 16 + lm;
        int rb = wn * 64 + i * 16 + lm;
        aoffL[i] = ra * 32 + ((q ^ ((ra >> 1) & 3)) * 8);
        boffL[i] = rb * 32 + ((q ^ ((rb >> 1) & 3)) * 8);
    }

    auto stage = [&](int buf, int kt) {
#pragma unroll
        for (int it = 0; it < 2; ++it) {
            gload_lds16(aG[it] + (long)kt * 32,        &sm[buf][0][ldsOff[it]]);
            gload_lds16(bG[it] + (long)kt * 32,        &sm[buf][1][ldsOff[it]]);
            gload_lds16(bG[it] + off3 + (long)kt * 32, &sm[buf][2][ldsOff[it]]);
        }
    };

    const int NT = Dm / 32;            // 32
    stage(0, 0);
    stage(1, 1);
    int cur = 0;
    for (int kt = 0; kt < NT; ++kt) {
        if (kt < NT - 1)
            asm volatile("s_waitcnt vmcnt(6) lgkmcnt(0)" ::: "memory");
        else
            asm volatile("s_waitcnt vmcnt(0) lgkmcnt(0)" ::: "memory");
        asm volatile("s_barrier" ::: "memory");
        if (kt + 2 < NT) {
            int nb = cur + 2; if (nb >= 3) nb -= 3;
            stage(nb, kt + 2);
        }
        const bf16* A_  = &sm[cur][0][0];
        const bf16* B1_ = &sm[cur][1][0];
        const bf16* B3_ = &sm[cur][2][0];
        bf16x8 af[4], b1v[4], b3v[4];
#pragma unroll
        for (int i = 0; i < 4; ++i) {
            af[i]  = *(const bf16x8*)(A_  + aoffL[i]);
            b1v[i] = *(const bf16x8*)(B1_ + boffL[i]);
            b3v[i] = *(const bf16x8*)(B3_ + boffL[i]);
        }
#pragma unroll
        for (int i = 0; i < 4; ++i)
#pragma unroll
            for (int j2 = 0; j2 < 4; ++j2) {
                acc1[i][j2] = __builtin_amdgcn_mfma_f32_16x16x32_bf16(
                    af[i], b1v[j2], acc1[i][j2], 0, 0, 0);
                acc3[i][j2] = __builtin_amdgcn_mfma_f32_16x16x32_bf16(
                    af[i], b3v[j2], acc3[i][j2], 0, 0, 0);
            }
        cur = (cur == 2) ? 0 : cur + 1;
    }

    int colbase = ntile * 128 + wn * 64;
#pragma unroll
    for (int i = 0; i < 4; ++i) {
        int rloc = wm * 64 + i * 16 + q * 4;
#pragma unroll
        for (int r = 0; r < 4; ++r) {
            int rl = mt * 128 + rloc + r;
            if (rl >= mcount) continue;
#pragma unroll
            for (int j2 = 0; j2 < 4; ++j2) {
                int col = colbase + j2 * 16 + lm;
                float a = acc1[i][j2][r], b = acc3[i][j2][r];
                float sg = 1.0f / (1.0f + __expf(-a));
                outH[(long)(rowbase + rl) * ldo + col] = (bf16)(a * sg * b);
            }
        }
    }
}

// Merged GEMM2: same depth-2 counted-vmcnt pipeline (S=4 -> vmcnt(4)).
// Flat 4352-block grid, BALANCED XCD-chunked decode: XCD i = bid&7,
// rank r = bid>>3 in [0,544):
//   r < 512  -> routed: e = 4i + (r>>7), nt = (r>>4)&7, mt = r&15
//               (A=Hh K=512, bf16 compact store to Yc)
//   r >= 512 -> shared: mt = 4i + ((r-512)>>3), nt = (r-512)&7
//               (A=HhS K=1024, fp32 store to out)
__global__ void __launch_bounds__(256, 2) gemm2_merged(
    const bf16* __restrict__ Hh, const bf16* __restrict__ HhS,
    const bf16* __restrict__ W2T, const bf16* __restrict__ Ws2T,
    const int* __restrict__ cntc, const int* __restrict__ offs,
    bf16* __restrict__ Yc, float* __restrict__ out)
{
    __shared__ __align__(16) bf16 sm[3][2][128 * 32];   // 48 KB (3buf A,B)

    int bid = blockIdx.x;
    int xcd = bid & 7, rk = bid >> 3;   // rk in [0,544)

    int mt, mcount, rowbase, K, lda, nt;
    const bf16* A;
    const bf16* BT;
    bool toBf;
    if (rk < 512) {
        int e = xcd * 4 + (rk >> 7);
        nt = (rk >> 4) & 7;
        mt = rk & 15;
        mcount = cntc[e];
        if (mt * 128 >= mcount) return;
        rowbase = offs[e];
        A = Hh; lda = Hm; K = Hm;
        BT = W2T + (long)e * Hm * Dm;
        toBf = true;
    } else {
        int s = rk - 512;              // [0,32): 4 mt x 8 nt per XCD
        mt = xcd * 4 + (s >> 3);
        nt = s & 7;
        mcount = T_TOK; rowbase = 0;
        A = HhS; lda = HsDim; K = HsDim;
        BT = Ws2T;
        toBf = false;
    }

    int tid = threadIdx.x;
    int wave = tid >> 6, lane = tid & 63;
    int wm = wave >> 1, wn = wave & 1;
    int q = lane >> 4, lm = lane & 15;

    floatx4 acc[4][4] = {};

    const bf16* aG[2];
    const bf16* bG[2];
    int ldsOff[2];
#pragma unroll
    for (int it = 0; it < 2; ++it) {
        int c = wave * 128 + it * 64 + lane;
        int row = c >> 2;
        int g = (c & 3) ^ ((row >> 1) & 3);
        int rl = mt * 128 + row;
        int rr = rl < mcount ? rl : mcount - 1;
        aG[it] = A + (long)(rowbase + rr) * lda + g * 8;
        bG[it] = BT + (long)(nt * 128 + row) * K + g * 8;
        ldsOff[it] = (wave * 128 + it * 64) * 8;
    }

    int aoffL[4], boffL[4];
#pragma unroll
    for (int i = 0; i < 4; ++i) {
        int ra = wm * 64 + i * 16 + lm;
        int rb = wn * 64 + i * 16 + lm;
        aoffL[i] = ra * 32 + ((q ^ ((ra >> 1) & 3)) * 8);
        boffL[i] = rb * 32 + ((q ^ ((rb >> 1) & 3)) * 8);
    }

    auto stage = [&](int buf, int kt) {
#pragma unroll
        for (int it = 0; it < 2; ++it) {
            gload_lds16(aG[it] + (long)kt * 32, &sm[buf][0][ldsOff[it]]);
            gload_lds16(bG[it] + (long)kt * 32, &sm[buf][1][ldsOff[it]]);
        }
    };

    const int NT = K / 32;             // 16 or 32 (block-uniform)
    stage(0, 0);
    stage(1, 1);
    int cur = 0;
    for (int kt = 0; kt < NT; ++kt) {
        if (kt < NT - 1)
            asm volatile("s_waitcnt vmcnt(4) lgkmcnt(0)" ::: "memory");
        else
            asm volatile("s_waitcnt vmcnt(0) lgkmcnt(0)" ::: "memory");
        asm volatile("s_barrier" ::: "memory");
        if (kt + 2 < NT) {
            int nb = cur + 2; if (nb >= 3) nb -= 3;
            stage(nb, kt + 2);
        }
        const bf16* A_ = &sm[cur][0][0];
        const bf16* B_ = &sm[cur][1][0];
        bf16x8 af[4], bfv[4];
#pragma unroll
        for (int i = 0; i < 4; ++i) {
            af[i]  = *(const bf16x8*)(A_ + aoffL[i]);
            bfv[i] = *(const bf16x8*)(B_ + boffL[i]);
        }
#pragma unroll
        for (int i = 0; i < 4; ++i)
#pragma unroll
            for (int j2 = 0; j2 < 4; ++j2)
                acc[i][j2] = __builtin_amdgcn_mfma_f32_16x16x32_bf16(
                    af[i], bfv[j2], acc[i][j2], 0, 0, 0);
        cur = (cur == 2) ? 0 : cur + 1;
    }

    int colbase = nt * 128 + wn * 64;
#pragma unroll
    for (int i = 0; i < 4; ++i) {
        int rloc = wm * 64 + i * 16 + q * 4;
#pragma unroll
        for (int r = 0; r < 4; ++r) {
            int rl = mt * 128 + rloc + r;
            if (rl >= mcount) continue;
#pragma unroll
            for (int j2 = 0; j2 < 4; ++j2) {
                int col = colbase + j2 * 16 + lm;
                float v = acc[i][j2][r];
                if (toBf) Yc[(long)(rowbase + rl) * Dm + col] = (bf16)v;
                else      out[(long)rl * Dm + col] = v;
            }
        }
    }
}

// ------------------------------------------------------------- combine ------
// out[t][:] += sum_k w[t,k] * Yc[posC[t*4+k]][:]  (posC<0 => dropped pair).
__global__ __launch_bounds__(256) void combine_kernel(
    const bf16* __restrict__ Yc, const float* __restrict__ topkW,
    const int* __restrict__ posC, float* __restrict__ out)
{
    __shared__ int   sp[4];
    __shared__ float sw[4];
    int t = blockIdx.x, tid = threadIdx.x;
    if (tid < 4) {
        sp[tid] = posC[t * 4 + tid];
        sw[tid] = topkW[t * 4 + tid];
    }
    __syncthreads();
    int d = tid * 4;
    float4 o = *(float4*)(out + (size_t)t * Dm + d);
#pragma unroll
    for (int k = 0; k < 4; ++k) {
        int rc = sp[k];
        if (rc >= 0) {
            bf16x4 v = *(const bf16x4*)(Yc + (size_t)rc * Dm + d);
            float w = sw[k];
            o.x += w * (float)v[0];
            o.y += w * (float)v[1];
            o.z += w * (float)v[2];
            o.w += w * (float)v[3];
        }
    }
    *(float4*)(out + (size_t)t * Dm + d) = o;
}

// ---------------------------------------------------------------- launch ----
extern "C" void kernel_launch(void* const* d_in, const int* in_sizes, int n_in,
                              void* d_out, int out_size, void* d_ws, size_t ws_size,
                              hipStream_t stream)
{
    const float* x   = (const float*)d_in[0];
    const float* Wg  = (const float*)d_in[1];
    const float* W1  = (const float*)d_in[2];
    const float* W2  = (const float*)d_in[3];
    const float* W3  = (const float*)d_in[4];
    const float* Ws1 = (const float*)d_in[5];
    const float* Ws2 = (const float*)d_in[6];
    const float* Ws3 = (const float*)d_in[7];
    float* out = (float*)d_out;

    char* p = (char*)d_ws;
    auto alloc = [&](size_t bytes) {
        char* r = p; p += (bytes + 255) & ~(size_t)255; return r;
    };
    bf16*  xb    = (bf16*)alloc((size_t)T_TOK * Dm * 2);
    bf16*  W13T  = (bf16*)alloc((size_t)Em * 2 * Hm * Dm * 2);
    bf16*  W2T   = (bf16*)alloc((size_t)Em * Dm * Hm * 2);
    bf16*  Ws13T = (bf16*)alloc((size_t)2 * HsDim * Dm * 2);
    bf16*  Ws2T  = (bf16*)alloc((size_t)Dm * HsDim * 2);
    bf16*  Yc    = (bf16*)alloc((size_t)Pp * Dm * 2);      // expert GEMM2 compact out
    bf16*  Hh    = (bf16*)alloc((size_t)Pp * Hm * 2);      // expert hidden (compact)
    bf16*  HhS   = (bf16*)alloc((size_t)T_TOK * HsDim * 2);// shared hidden
    float* logits= (float*)alloc((size_t)T_TOK * Em * 4);
    int*   topkE = (int*)alloc(Pp * 4);
    float* topkW = (float*)alloc(Pp * 4);
    int*   tokC  = (int*)alloc(Pp * 4);
    float* wtC   = (float*)alloc(Pp * 4);
    int*   posC  = (int*)alloc(Pp * 4);
    int*   cnt   = (int*)alloc(128);
    int*   cnt2  = (int*)alloc(128);
    int*   cntc  = (int*)alloc(128);
    int*   offs  = (int*)alloc(256);

    size_t need = (size_t)(p - (char*)d_ws);
    if (ws_size < need) {
        fprintf(stderr, "kernel_launch: ws too small (%zu < %zu)\n", ws_size, need);
        return;
    }

    hipMemsetAsync(cnt, 0, 1024, stream);  // cnt, cnt2, cntc, offs

    // Routing (fp32, matches reference top-k exactly) + x bf16 cast
    gate_logits<<<T_TOK / 8, 256, 0, stream>>>(x, Wg, logits, xb);
    gate_topk<<<T_TOK / 256, 256, 0, stream>>>(logits, topkE, topkW, cnt);
    offsets_kernel<<<1, 64, 0, stream>>>(cnt, cntc, offs);
    scatter_kernel<<<Pp / 256, 256, 0, stream>>>(topkE, topkW, cntc, offs, cnt2,
                                                 tokC, wtC, posC);

    // weight transposes+casts (3 dispatches)
    transpose_w13<<<dim3(Hm / 64, Dm / 64, 2 * Em), dim3(64, 4), 0, stream>>>(W1, W3, W13T);
    transpose_w2 <<<dim3(Dm / 64, Hm / 64, Em),     dim3(64, 4), 0, stream>>>(W2, W2T);
    transpose_ws <<<dim3(Dm / 64, Dm / 64, 3),      dim3(64, 4), 0, stream>>>(
        Ws1, Ws3, Ws2, Ws13T, Ws2T);

    // GEMM1 (both paths, fused SwiGLU) -> GEMM2 (both paths) -> combine
    gemm1_merged<<<dim3(2304), 256, 0, stream>>>(
        xb, W13T, Ws13T, cntc, offs, tokC, Hh, HhS);
    gemm2_merged<<<dim3(4352), 256, 0, stream>>>(
        Hh, HhS, W2T, Ws2T, cntc, offs, Yc, out);
    combine_kernel<<<T_TOK, 256, 0, stream>>>(Yc, topkW, posC, out);
}